// Round 13
// baseline (549.933 us; speedup 1.0000x reference)
//
#include <hip/hip_runtime.h>
#include <hip/hip_fp16.h>
#include <math.h>

typedef unsigned short u16;
typedef short s16x8 __attribute__((ext_vector_type(8)));
typedef unsigned short u16x8 __attribute__((ext_vector_type(8)));
typedef _Float16 f16x8 __attribute__((ext_vector_type(8)));
typedef float f32x4 __attribute__((ext_vector_type(4)));

// ---------- helpers ----------
__device__ __forceinline__ float bf2f(u16 u) {
  unsigned x = ((unsigned)u) << 16;
  return __uint_as_float(x);
}
__device__ __forceinline__ u16 f2bf(float f) {
  unsigned x = __float_as_uint(f);
  unsigned r = x + 0x7FFFu + ((x >> 16) & 1u);
  return (u16)(r >> 16);
}
__device__ __forceinline__ u16 f2h(float f) {
  __half h = __float2half_rn(f);
  return *reinterpret_cast<u16*>(&h);
}

// ---------- ws layout (bytes) ----------
static const size_t OFF_MINV   = 0;
static const size_t OFF_AU     = 32ull * 1024;
static const size_t OFF_BUE    = 32ull * 1024 + 256;
static const size_t OFF_AP     = 32ull * 1024 + 512;
static const size_t OFF_APBE   = 32ull * 1024 + 768;
static const size_t OFF_AM     = 36ull * 1024;
static const size_t OFF_BM     = 37ull * 1024;
static const size_t OFF_AF     = 38ull * 1024;
static const size_t OFF_BF     = 39ull * 1024;
static const size_t OFF_BTOT   = 40ull * 1024;
static const size_t OFF_BOFF   = 44ull * 1024;
static const size_t OFF_WUT    = 64ull * 1024;
static const size_t OFF_WMT    = 128ull * 1024;
static const size_t OFF_WFT    = 192ull * 1024;
static const size_t OFF_WPH    = 512ull * 1024;            // Wp^T f16 [64][256]
static const size_t OFF_PART1A = 1ull  * 1024 * 1024;
static const size_t OFF_PART1B = 1ull  * 1024 * 1024 + 512 * 1024;
static const size_t OFF_PART2A = 2ull  * 1024 * 1024;
static const size_t OFF_PART2B = 2ull  * 1024 * 1024 + 512 * 1024;
static const size_t OFF_ROWPTR = 3ull  * 1024 * 1024;
static const size_t OFF_BLKCNT = 5ull  * 1024 * 1024;     // counts 2MB; HB bf16 reuses 5..17.8MB later
static const size_t OFF_BLKOFF = 7ull  * 1024 * 1024;     // offsets 2MB (dead after kA3)
static const size_t OFF_SRCJ   = 18ull * 1024 * 1024;     // E int; dead after k_nodeall -> RAWO bf16 N*256
static const size_t OFF_U      = 44ull * 1024 * 1024;     // UBRAW bf16 N*64
static const size_t OFF_P      = 70ull * 1024 * 1024;     // TMP uint E (dead after kB)
static const size_t OFF_PS     = 109ull * 1024 * 1024;    // raw su f16 N*64
static const size_t OFF_H2     = 122ull * 1024 * 1024;

#define NBLK_BIN 1024

// ---------- merged: weight transpose/convert (blocks 0..703) + Minv prep (block 704) ----------
__global__ __launch_bounds__(256) void k_tcvt_prep(const float* __restrict__ Wu, const float* __restrict__ Wm,
                                                   const float* __restrict__ Wf, const float* __restrict__ Wp,
                                                   u16* __restrict__ WUT, u16* __restrict__ WMT,
                                                   u16* __restrict__ WFT, u16* __restrict__ WPH,
                                                   const float* __restrict__ c, float* __restrict__ minv_out) {
  int b = blockIdx.x, t = threadIdx.x;
  if (b < 64) {
    int i = b * 256 + t;
    int k = i >> 6, n = i & 63;
    WUT[(size_t)n * 256 + k] = f2bf(Wu[i]);
    return;
  } else if (b < 128) {
    int i = (b - 64) * 256 + t;
    int k = i >> 8, n = i & 255;
    WMT[(size_t)n * 64 + k] = f2bf(Wm[i]);
    return;
  } else if (b < 640) {
    int i = (b - 128) * 256 + t;
    int k = i >> 8, n = i & 255;
    WFT[(size_t)n * 512 + k] = f2bf(Wf[i]);
    return;
  } else if (b < 704) {
    int i = (b - 640) * 256 + t;
    int k = i >> 6, n = i & 63;
    WPH[(size_t)n * 256 + k] = f2h(Wp[i]);
    return;
  }
  // ---- block 704: Minv = (I + c^T c)^-1 (conflict-free GJ, deferred normalization) ----
  __shared__ float CC[4096];
  __shared__ float aug[64 * 129];
  __shared__ float fs[64];
  float* cl = aug;
  for (int idx = t; idx < 4096; idx += 256) cl[idx] = c[idx];
  __syncthreads();
  for (int idx = t; idx < 4096; idx += 256) {
    int a = idx >> 6, bb = idx & 63;
    float s = (a == bb) ? 1.f : 0.f;
    for (int k = 0; k < 64; ++k) s += cl[k * 64 + a] * cl[k * 64 + bb];
    CC[idx] = s;
  }
  __syncthreads();
  for (int idx = t; idx < 8192; idx += 256) {
    int r = idx >> 7, cc = idx & 127;
    aug[r * 129 + cc] = (cc < 64) ? CC[r * 64 + cc] : (((cc - 64) == r) ? 1.f : 0.f);
  }
  __syncthreads();
  int cloc = t & 127;
  int rbase = t >> 7;
  for (int p = 0; p < 64; ++p) {
    if (t < 64) fs[t] = (t == p) ? 0.f : aug[t * 129 + p] / aug[p * 129 + p];
    __syncthreads();
    float pc = aug[p * 129 + cloc];
#pragma unroll
    for (int rr = 0; rr < 64; rr += 2) {
      int r = rr + rbase;
      aug[r * 129 + cloc] -= fs[r] * pc;
    }
    __syncthreads();
  }
  for (int idx = t; idx < 4096; idx += 256) {
    int r = idx >> 6, cc = idx & 63;
    minv_out[idx] = aug[r * 129 + 64 + cc] / aug[r * 129 + r];
  }
}

// ---------- binned CSR build ----------
__global__ __launch_bounds__(256) void kA1(const int* __restrict__ ei, int E, int chunk,
                                           int* __restrict__ blockCnt, int nbk) {
  __shared__ int c[512];
  int t = threadIdx.x, bid = blockIdx.x;
  c[t] = 0; c[t + 256] = 0;
  __syncthreads();
  int e0 = bid * chunk, e1 = min(E, e0 + chunk);
  for (int e = e0 + t; e < e1; e += 256) atomicAdd(&c[ei[e] >> 8], 1);
  __syncthreads();
  for (int b = t; b < nbk; b += 256) blockCnt[(size_t)bid * nbk + b] = c[b];
}

// kA2: per-bucket exclusive scan over blocks; counts preserved, offsets to blkOff
__global__ __launch_bounds__(256) void kA2(const int* __restrict__ blockCnt, int nbk,
                                           int* __restrict__ blkOff, int* __restrict__ bucketTot) {
  int b = blockIdx.x, t = threadIdx.x;
  int base = t * 4;
  int v0 = blockCnt[(size_t)(base + 0) * nbk + b];
  int v1 = blockCnt[(size_t)(base + 1) * nbk + b];
  int v2 = blockCnt[(size_t)(base + 2) * nbk + b];
  int v3 = blockCnt[(size_t)(base + 3) * nbk + b];
  int s1 = v0 + v1, s2 = s1 + v2, tot = s2 + v3;
  __shared__ int ps[256];
  ps[t] = tot;
  __syncthreads();
  for (int off = 1; off < 256; off <<= 1) {
    int a = (t >= off) ? ps[t - off] : 0;
    __syncthreads();
    ps[t] += a;
    __syncthreads();
  }
  int ex = (t > 0) ? ps[t - 1] : 0;
  blkOff[(size_t)(base + 0) * nbk + b] = ex;
  blkOff[(size_t)(base + 1) * nbk + b] = ex + v0;
  blkOff[(size_t)(base + 2) * nbk + b] = ex + s1;
  blkOff[(size_t)(base + 3) * nbk + b] = ex + s2;
  if (t == 255) bucketTot[b] = ps[255];
}

__global__ __launch_bounds__(512) void kA2b(const int* __restrict__ bucketTot,
                                            int* __restrict__ bucketOff, int nbk) {
  __shared__ int s[512];
  int t = threadIdx.x;
  s[t] = (t < nbk) ? bucketTot[t] : 0;
  __syncthreads();
  for (int off = 1; off < 512; off <<= 1) {
    int a = (t >= off) ? s[t - off] : 0;
    __syncthreads();
    s[t] += a;
    __syncthreads();
  }
  if (t == 0) bucketOff[0] = 0;
  if (t < nbk) bucketOff[t + 1] = s[t];
}

// A3: reload counts (no re-histogram), LDS counting-sort, packed 4B runs to TMP
__global__ __launch_bounds__(256) void kA3(const int* __restrict__ ei, const int* __restrict__ ej,
                                           int E, int chunk,
                                           const int* __restrict__ blockCnt,
                                           const int* __restrict__ blkOff,
                                           const int* __restrict__ bucketOff,
                                           int nbk, unsigned* __restrict__ tmp) {
  __shared__ int off[512], gb[512], cur[512];
  __shared__ uint2 stage[4096];
  int t = threadIdx.x, bid = blockIdx.x;
  int v0 = (t < nbk) ? blockCnt[(size_t)bid * nbk + t] : 0;
  int v1 = (t + 256 < nbk) ? blockCnt[(size_t)bid * nbk + t + 256] : 0;
  off[t] = v0; off[t + 256] = v1;
  __syncthreads();
  for (int o = 1; o < 512; o <<= 1) {
    int a0 = (t >= o) ? off[t - o] : 0;
    int a1 = ((t + 256) >= o) ? off[t + 256 - o] : 0;
    __syncthreads();
    off[t] += a0; off[t + 256] += a1;
    __syncthreads();
  }
  int ex0 = off[t] - v0, ex1 = off[t + 256] - v1;
  if (t < nbk)
    gb[t] = bucketOff[t] + blkOff[(size_t)bid * nbk + t] - ex0;
  if (t + 256 < nbk)
    gb[t + 256] = bucketOff[t + 256] + blkOff[(size_t)bid * nbk + t + 256] - ex1;
  cur[t] = ex0; cur[t + 256] = ex1;
  __syncthreads();
  int e0 = bid * chunk, e1 = min(E, e0 + chunk);
  int m = e1 - e0;
  for (int e = e0 + t; e < e1; e += 256) {
    int i = ei[e];
    int p = atomicAdd(&cur[i >> 8], 1);
    stage[p] = make_uint2((unsigned)i, (unsigned)ej[e]);
  }
  __syncthreads();
  for (int s = t; s < m; s += 256) {
    uint2 v = stage[s];
    tmp[gb[v.x >> 8] + s] = ((v.x & 255u) << 24) | v.y;
  }
}

#define BCAP 12288
__global__ __launch_bounds__(256) void kB(const unsigned* __restrict__ tmp,
                                          const int* __restrict__ bucketOff,
                                          int nbk, int N, int E,
                                          int* __restrict__ rowptr, int* __restrict__ srcj) {
  __shared__ int cnt[256], sc[256], cur[256];
  __shared__ int jbuf[BCAP];
  int b = blockIdx.x, t = threadIdx.x;
  int nb0 = b << 8;
  int e0 = bucketOff[b], e1 = bucketOff[b + 1];
  int m = e1 - e0;
  cnt[t] = 0;
  __syncthreads();
  for (int s = t; s < m; s += 256) atomicAdd(&cnt[tmp[e0 + s] >> 24], 1);
  __syncthreads();
  int v = cnt[t];
  sc[t] = v;
  __syncthreads();
  for (int off = 1; off < 256; off <<= 1) {
    int a = (t >= off) ? sc[t - off] : 0;
    __syncthreads();
    sc[t] += a;
    __syncthreads();
  }
  int exc = sc[t] - v;
  cur[t] = exc;
  if (nb0 + t < N) rowptr[nb0 + t] = e0 + exc;
  if (b == nbk - 1 && t == 0) rowptr[N] = E;
  __syncthreads();
  for (int s = t; s < m; s += 256) {
    unsigned e = tmp[e0 + s];
    int p = atomicAdd(&cur[e >> 24], 1);
    if (p < BCAP) jbuf[p] = (int)(e & 0xFFFFFFu);
  }
  __syncthreads();
  for (int s = t; s < m; s += 256) srcj[e0 + s] = jbuf[s];
}

// ---------- MFMA GEMM BM=128 x BN=64 (skinny paths) ----------
// AMODE 0: A bf16. AMODE 2: A f32 converted in staging. OBF: 0 f32, 1 bf16, 2 f16 out.
template<int BN, int AMODE, int OBF, int STATS, int FP16>
__global__ __launch_bounds__(256) void k_mfma(const u16* __restrict__ Abf, const float* __restrict__ Af32,
                                              int ldA, int K, int M,
                                              const u16* __restrict__ Bt,
                                              float* __restrict__ Cf, u16* __restrict__ Cb, int ldC,
                                              int ncTot, float* __restrict__ p1, float* __restrict__ p2) {
  constexpr int WN  = BN / 2;
  constexpr int FN  = WN / 16;
  constexpr int NPB = BN / 32;
  __shared__ u16 lds[2][(128 + BN) * 64];

  int t = threadIdx.x;
  int wid = t >> 6, lane = t & 63;
  int wr = wid >> 1, wc = wid & 1;
  int lr = lane & 15, lk = lane >> 4;
  int m0 = blockIdx.x * 128;
  int n0 = blockIdx.y * BN;
  int nK = K >> 6;

  int sidx = t;
  u16x8 ra[4];
  u16x8 rb[NPB];

  f32x4 acc[4][FN];
#pragma unroll
  for (int m = 0; m < 4; ++m)
#pragma unroll
    for (int n = 0; n < FN; ++n) acc[m][n] = (f32x4){0.f, 0.f, 0.f, 0.f};

  auto loadTile = [&](int kk) {
    int kk0 = kk * 64;
#pragma unroll
    for (int p = 0; p < 4; ++p) {
      int idx = p * 256 + sidx;
      int r = idx >> 3, c8 = idx & 7;
      int row = m0 + r; if (row >= M) row = M - 1;
      int k = kk0 + c8 * 8;
      if constexpr (AMODE == 0) {
        ra[p] = *(const u16x8*)(Abf + (size_t)row * ldA + k);
      } else {
        const float* src = Af32 + (size_t)row * ldA + k;
        float4 a = *(const float4*)src;
        float4 b = *(const float4*)(src + 4);
        u16x8 o;
        if constexpr (FP16) {
          o[0] = f2h(a.x); o[1] = f2h(a.y); o[2] = f2h(a.z); o[3] = f2h(a.w);
          o[4] = f2h(b.x); o[5] = f2h(b.y); o[6] = f2h(b.z); o[7] = f2h(b.w);
        } else {
          o[0] = f2bf(a.x); o[1] = f2bf(a.y); o[2] = f2bf(a.z); o[3] = f2bf(a.w);
          o[4] = f2bf(b.x); o[5] = f2bf(b.y); o[6] = f2bf(b.z); o[7] = f2bf(b.w);
        }
        ra[p] = o;
      }
    }
#pragma unroll
    for (int p = 0; p < NPB; ++p) {
      int idx = p * 256 + sidx;
      int r = idx >> 3, c8 = idx & 7;
      rb[p] = *(const u16x8*)(Bt + (size_t)(n0 + r) * K + kk0 + c8 * 8);
    }
  };

  auto dswrite = [&](int b) {
    char* As  = (char*)&lds[b][0];
    char* Bsc = As + 128 * 64 * 2;
#pragma unroll
    for (int p = 0; p < 4; ++p) {
      int idx = p * 256 + sidx;
      int r = idx >> 3, c8 = idx & 7;
      *(u16x8*)(As + r * 128 + ((c8 * 16) ^ ((r & 7) << 4))) = ra[p];
    }
#pragma unroll
    for (int p = 0; p < NPB; ++p) {
      int idx = p * 256 + sidx;
      int r = idx >> 3, c8 = idx & 7;
      *(u16x8*)(Bsc + r * 128 + ((c8 * 16) ^ ((r & 7) << 4))) = rb[p];
    }
  };

  auto compute = [&](int b) {
    const char* As  = (const char*)&lds[b][0];
    const char* Bsc = As + 128 * 64 * 2;
#pragma unroll
    for (int ks = 0; ks < 2; ++ks) {
      int kb = ks * 64 + lk * 16;
#pragma unroll
      for (int m = 0; m < 4; ++m) {
        int rowA = wr * 64 + m * 16 + lr;
        const char* pa = As + rowA * 128 + (kb ^ ((rowA & 7) << 4));
#pragma unroll
        for (int n = 0; n < FN; ++n) {
          int rowB = wc * WN + n * 16 + lr;
          const char* pb = Bsc + rowB * 128 + (kb ^ ((rowB & 7) << 4));
          if constexpr (FP16) {
            f16x8 af = *(const f16x8*)pa;
            f16x8 bf = *(const f16x8*)pb;
            acc[m][n] = __builtin_amdgcn_mfma_f32_16x16x32_f16(af, bf, acc[m][n], 0, 0, 0);
          } else {
            s16x8 af = *(const s16x8*)pa;
            s16x8 bf = *(const s16x8*)pb;
            acc[m][n] = __builtin_amdgcn_mfma_f32_16x16x32_bf16(af, bf, acc[m][n], 0, 0, 0);
          }
        }
      }
    }
  };

  loadTile(0);
  dswrite(0);
  __syncthreads();
  for (int kk = 0; kk < nK; ++kk) {
    int b = kk & 1;
    if (kk + 1 < nK) loadTile(kk + 1);
    compute(b);
    if (kk + 1 < nK) { dswrite(b ^ 1); __syncthreads(); }
  }

#pragma unroll
  for (int m = 0; m < 4; ++m) {
#pragma unroll
    for (int n = 0; n < FN; ++n) {
      int col = n0 + wc * WN + n * 16 + lr;
#pragma unroll
      for (int q = 0; q < 4; ++q) {
        int row = m0 + wr * 64 + m * 16 + lk * 4 + q;
        if (row < M) {
          if constexpr (OBF == 2)      Cb[(size_t)row * ldC + col] = f2h(acc[m][n][q]);
          else if constexpr (OBF == 1) Cb[(size_t)row * ldC + col] = f2bf(acc[m][n][q]);
          else                         Cf[(size_t)row * ldC + col] = acc[m][n][q];
        }
      }
    }
  }

  if constexpr (STATS) {
    __syncthreads();
    float* sb = (float*)&lds[0][0];
#pragma unroll
    for (int n = 0; n < FN; ++n) {
      float s1 = 0.f, s2 = 0.f;
#pragma unroll
      for (int m = 0; m < 4; ++m)
#pragma unroll
        for (int q = 0; q < 4; ++q) {
          int row = m0 + wr * 64 + m * 16 + lk * 4 + q;
          float v = (row < M) ? acc[m][n][q] : 0.f;
          s1 += v; s2 += v * v;
        }
      s1 += __shfl_xor(s1, 16); s2 += __shfl_xor(s2, 16);
      s1 += __shfl_xor(s1, 32); s2 += __shfl_xor(s2, 32);
      if (lk == 0) {
        int c = wc * WN + n * 16 + lr;
        sb[(wr * BN + c) * 2 + 0] = s1;
        sb[(wr * BN + c) * 2 + 1] = s2;
      }
    }
    __syncthreads();
    if (t < BN) {
      float s1 = sb[t * 2]     + sb[(BN + t) * 2];
      float s2 = sb[t * 2 + 1] + sb[(BN + t) * 2 + 1];
      p1[(size_t)blockIdx.x * ncTot + n0 + t] = s1;
      p2[(size_t)blockIdx.x * ncTot + n0 + t] = s2;
    }
  }
}

// ---------- MFMA GEMM2: BM=128 x BN=256, single-buffered LDS ----------
template<int AMODE>
__global__ __launch_bounds__(512) void k_mfma2(const u16* __restrict__ Abf, int ldA, int K, int M,
                                               const u16* __restrict__ h2, const float* __restrict__ yy,
                                               const float* __restrict__ am, const float* __restrict__ bm,
                                               const u16* __restrict__ Bt,
                                               u16* __restrict__ Cb,
                                               float* __restrict__ p1, float* __restrict__ p2) {
  __shared__ u16 lds[(128 + 256) * 64];
  int t = threadIdx.x;
  int wid = t >> 6, lane = t & 63;
  int wr = wid >> 2, wc = wid & 3;
  int lr = lane & 15, lk = lane >> 4;
  int m0 = blockIdx.x * 128;
  int nK = K >> 6;

  u16x8 ra[2];
  u16x8 rb[4];
  f32x4 acc[4][4];
#pragma unroll
  for (int m = 0; m < 4; ++m)
#pragma unroll
    for (int n = 0; n < 4; ++n) acc[m][n] = (f32x4){0.f, 0.f, 0.f, 0.f};

  auto loadTile = [&](int kk) {
    int kk0 = kk * 64;
#pragma unroll
    for (int p = 0; p < 2; ++p) {
      int idx = p * 512 + t;
      int r = idx >> 3, c8 = idx & 7;
      int row = m0 + r; if (row >= M) row = M - 1;
      int k = kk0 + c8 * 8;
      if constexpr (AMODE == 0) {
        ra[p] = *(const u16x8*)(Abf + (size_t)row * ldA + k);
      } else {
        if (kk0 < 256) {
          u16x8 h8 = *(const u16x8*)(h2 + (size_t)row * 256 + k);
          float av[8], bv[8];
          *(float4*)(av)     = *(const float4*)(am + k);
          *(float4*)(av + 4) = *(const float4*)(am + k + 4);
          *(float4*)(bv)     = *(const float4*)(bm + k);
          *(float4*)(bv + 4) = *(const float4*)(bm + k + 4);
          u16x8 o;
#pragma unroll
          for (int j = 0; j < 8; ++j) {
            float v = bf2f((u16)h8[j]) * av[j] + bv[j];
            v = v > 0.f ? v : 0.01f * v;
            o[j] = f2bf(v);
          }
          ra[p] = o;
        } else {
          float yv[8];
          *(float4*)(yv)     = *(const float4*)(yy + (size_t)row * 256 + (k - 256));
          *(float4*)(yv + 4) = *(const float4*)(yy + (size_t)row * 256 + (k - 256) + 4);
          u16x8 o;
#pragma unroll
          for (int j = 0; j < 8; ++j) o[j] = f2bf(yv[j]);
          ra[p] = o;
        }
      }
    }
#pragma unroll
    for (int p = 0; p < 4; ++p) {
      int idx = p * 512 + t;
      int r = idx >> 3, c8 = idx & 7;
      rb[p] = *(const u16x8*)(Bt + (size_t)r * K + kk0 + c8 * 8);
    }
  };

  auto dswrite = [&]() {
    char* As  = (char*)&lds[0];
    char* Bsc = As + 128 * 64 * 2;
#pragma unroll
    for (int p = 0; p < 2; ++p) {
      int idx = p * 512 + t;
      int r = idx >> 3, c8 = idx & 7;
      *(u16x8*)(As + r * 128 + ((c8 * 16) ^ ((r & 7) << 4))) = ra[p];
    }
#pragma unroll
    for (int p = 0; p < 4; ++p) {
      int idx = p * 512 + t;
      int r = idx >> 3, c8 = idx & 7;
      *(u16x8*)(Bsc + r * 128 + ((c8 * 16) ^ ((r & 7) << 4))) = rb[p];
    }
  };

  auto compute = [&]() {
    const char* As  = (const char*)&lds[0];
    const char* Bsc = As + 128 * 64 * 2;
#pragma unroll
    for (int ks = 0; ks < 2; ++ks) {
      int kb = ks * 64 + lk * 16;
      s16x8 af[4], bfr[4];
#pragma unroll
      for (int m = 0; m < 4; ++m) {
        int row = wr * 64 + m * 16 + lr;
        af[m] = *(const s16x8*)(As + row * 128 + (kb ^ ((row & 7) << 4)));
      }
#pragma unroll
      for (int n = 0; n < 4; ++n) {
        int row = wc * 64 + n * 16 + lr;
        bfr[n] = *(const s16x8*)(Bsc + row * 128 + (kb ^ ((row & 7) << 4)));
      }
#pragma unroll
      for (int m = 0; m < 4; ++m)
#pragma unroll
        for (int n = 0; n < 4; ++n)
          acc[m][n] = __builtin_amdgcn_mfma_f32_16x16x32_bf16(af[m], bfr[n], acc[m][n], 0, 0, 0);
    }
  };

  loadTile(0);
  for (int kk = 0; kk < nK; ++kk) {
    __syncthreads();
    dswrite();
    __syncthreads();
    if (kk + 1 < nK) loadTile(kk + 1);
    compute();
  }

#pragma unroll
  for (int m = 0; m < 4; ++m) {
#pragma unroll
    for (int n = 0; n < 4; ++n) {
      int col = wc * 64 + n * 16 + lr;
#pragma unroll
      for (int q = 0; q < 4; ++q) {
        int row = m0 + wr * 64 + m * 16 + lk * 4 + q;
        if (row < M) Cb[(size_t)row * 256 + col] = f2bf(acc[m][n][q]);
      }
    }
  }

  __syncthreads();
  float* sb = (float*)&lds[0];
#pragma unroll
  for (int n = 0; n < 4; ++n) {
    float s1 = 0.f, s2 = 0.f;
#pragma unroll
    for (int m = 0; m < 4; ++m)
#pragma unroll
      for (int q = 0; q < 4; ++q) {
        int row = m0 + wr * 64 + m * 16 + lk * 4 + q;
        float v = (row < M) ? acc[m][n][q] : 0.f;
        s1 += v; s2 += v * v;
      }
    s1 += __shfl_xor(s1, 16); s2 += __shfl_xor(s2, 16);
    s1 += __shfl_xor(s1, 32); s2 += __shfl_xor(s2, 32);
    if (lk == 0) {
      int c = wc * 64 + n * 16 + lr;
      sb[(wr * 256 + c) * 2 + 0] = s1;
      sb[(wr * 256 + c) * 2 + 1] = s2;
    }
  }
  __syncthreads();
  if (t < 256) {
    float s1 = sb[t * 2]     + sb[(256 + t) * 2];
    float s2 = sb[t * 2 + 1] + sb[(256 + t) * 2 + 1];
    p1[(size_t)blockIdx.x * 256 + t] = s1;
    p2[(size_t)blockIdx.x * 256 + t] = s2;
  }
}

// ---------- merged reduce: blocks 0-63 xu, 64-127 su ----------
__global__ __launch_bounds__(256) void k_reduce2(const float* __restrict__ p1a, const float* __restrict__ p2a,
                                                 const float* __restrict__ p1b, const float* __restrict__ p2b,
                                                 int nb, float invN,
                                                 const float* __restrict__ gu, const float* __restrict__ bu,
                                                 const float* __restrict__ gp, const float* __restrict__ bp,
                                                 float* __restrict__ AU, float* __restrict__ BUE,
                                                 float* __restrict__ AP, float* __restrict__ APBE) {
  int isB = blockIdx.x >> 6;
  int c = blockIdx.x & 63;
  int t = threadIdx.x;
  const float* part1 = isB ? p1b : p1a;
  const float* part2 = isB ? p2b : p2a;
  float s1 = 0.f, s2 = 0.f;
  for (int b = t; b < nb; b += 256) {
    s1 += part1[(size_t)b * 64 + c];
    s2 += part2[(size_t)b * 64 + c];
  }
  for (int m = 32; m; m >>= 1) { s1 += __shfl_xor(s1, m); s2 += __shfl_xor(s2, m); }
  __shared__ float l1[4], l2[4];
  if ((t & 63) == 0) { l1[t >> 6] = s1; l2[t >> 6] = s2; }
  __syncthreads();
  if (t == 0) {
    s1 = l1[0] + l1[1] + l1[2] + l1[3];
    s2 = l2[0] + l2[1] + l2[2] + l2[3];
    float mu  = s1 * invN;
    float var = s2 * invN - mu * mu;
    if (isB) {
      float a = gp[c] * rsqrtf(var + 1e-5f);
      AP[c] = a;
      APBE[c] = bp[c] - mu * a;
    } else {
      float a = gu[c] * rsqrtf(var + 1e-5f);
      AU[c] = a;
      BUE[c] = bu[c] - mu * a;
    }
  }
}

// ---------- reduce partials -> BN scale/shift (256 col) ----------
__global__ __launch_bounds__(256) void k_reduce_fin(const float* __restrict__ part1,
                                                    const float* __restrict__ part2,
                                                    int nb, int C, float invN,
                                                    const float* __restrict__ gamma,
                                                    const float* __restrict__ beta,
                                                    float* __restrict__ a_out,
                                                    float* __restrict__ b_out) {
  int c = blockIdx.x;
  int t = threadIdx.x;
  float s1 = 0.f, s2 = 0.f;
  for (int b = t; b < nb; b += 256) {
    s1 += part1[(size_t)b * C + c];
    s2 += part2[(size_t)b * C + c];
  }
  for (int m = 32; m; m >>= 1) { s1 += __shfl_xor(s1, m); s2 += __shfl_xor(s2, m); }
  __shared__ float l1[4], l2[4];
  if ((t & 63) == 0) { l1[t >> 6] = s1; l2[t >> 6] = s2; }
  __syncthreads();
  if (t == 0) {
    s1 = l1[0] + l1[1] + l1[2] + l1[3];
    s2 = l2[0] + l2[1] + l2[2] + l2[3];
    float mu  = s1 * invN;
    float var = s2 * invN - mu * mu;
    float a = gamma[c] * rsqrtf(var + 1e-5f);
    a_out[c] = a;
    b_out[c] = beta[c] - mu * a;
  }
}

// ---------- fused per-node: ap-scaled logits + softmax + RAW agg + BN + CRF solve ----------
__global__ __launch_bounds__(256) void k_nodeall(const __half* __restrict__ PS,
                                                 const int* __restrict__ srcj,
                                                 const int* __restrict__ rowptr,
                                                 const u16* __restrict__ UB,
                                                 const float* __restrict__ au,
                                                 const float* __restrict__ bue,
                                                 const float* __restrict__ ap,
                                                 const float* __restrict__ minv,
                                                 int N, u16* __restrict__ HB) {
  __shared__ float mS[4096];
  __shared__ float zma[4][64];
  int t = threadIdx.x;
  for (int idx = t; idx < 1024; idx += 256)
    ((float4*)mS)[idx] = ((const float4*)minv)[idx];
  __syncthreads();

  int lane = t & 63, wid = t >> 6;
  int node = blockIdx.x * 4 + wid;
  if (node >= N) return;

  int lane8 = lane & 7, g8 = lane >> 3;
  const uint4* P4 = (const uint4*)PS;
  float av[8];
  *(float4*)(av)     = *(const float4*)(ap + lane8 * 8);
  *(float4*)(av + 4) = *(const float4*)(ap + lane8 * 8 + 4);
  float apl = ap[lane];
  uint4 uv = P4[(size_t)node * 8 + lane8];
  float2 u0 = __half22float2(*(const __half2*)&uv.x);
  float2 u1 = __half22float2(((const __half2*)&uv.x)[1]);
  float2 u2 = __half22float2(*(const __half2*)&uv.z);
  float2 u3 = __half22float2(((const __half2*)&uv.z)[1]);
  u0.x *= av[0]; u0.y *= av[1]; u1.x *= av[2]; u1.y *= av[3];
  u2.x *= av[4]; u2.y *= av[5]; u3.x *= av[6]; u3.y *= av[7];
  float psl = __half2float(PS[(size_t)node * 64 + lane]);
  int b0 = rowptr[node], b1 = rowptr[node + 1];
  int deg = b1 - b0;
  float aggv = 0.f;
  if (deg > 0) {
    int cnt = deg < 64 ? deg : 64;
    int jj = (lane < cnt) ? srcj[b0 + lane] : 0;
    float lg = -INFINITY;
    int capbase = lane & ~7;
    int capsrc  = (lane & 7) << 3;

    auto logit8 = [&](uint4 vv) -> float {
      float2 v0 = __half22float2(*(const __half2*)&vv.x);
      float2 v1 = __half22float2(((const __half2*)&vv.x)[1]);
      float2 v2 = __half22float2(*(const __half2*)&vv.z);
      float2 v3 = __half22float2(((const __half2*)&vv.z)[1]);
      float d0 = fmaf(-av[0], v0.x, u0.x), d1 = fmaf(-av[1], v0.y, u0.y);
      float d2 = fmaf(-av[2], v1.x, u1.x), d3 = fmaf(-av[3], v1.y, u1.y);
      float d4 = fmaf(-av[4], v2.x, u2.x), d5 = fmaf(-av[5], v2.y, u2.y);
      float d6 = fmaf(-av[6], v3.x, u3.x), d7 = fmaf(-av[7], v3.y, u3.y);
      return d0*d0 + d1*d1 + d2*d2 + d3*d3 + d4*d4 + d5*d5 + d6*d6 + d7*d7;
    };

    // ---- logits: 16 edges in flight when possible, else one clamped 8-group ----
    int ss = 0;
    while (ss < cnt) {
      if (ss + 16 <= cnt) {
        int jA = __shfl(jj, ss + g8);
        int jB = __shfl(jj, ss + 8 + g8);
        uint4 vvA = P4[(size_t)jA * 8 + lane8];
        uint4 vvB = P4[(size_t)jB * 8 + lane8];
        float pA = logit8(vvA);
        float pB = logit8(vvB);
        pA += __shfl_xor(pA, 1, 8); pB += __shfl_xor(pB, 1, 8);
        pA += __shfl_xor(pA, 2, 8); pB += __shfl_xor(pB, 2, 8);
        pA += __shfl_xor(pA, 4, 8); pB += __shfl_xor(pB, 4, 8);
        float valA = __shfl(pA, capsrc);
        float valB = __shfl(pB, capsrc);
        if (ss == capbase && lane < cnt) lg = -valA;
        if (ss + 8 == capbase && lane < cnt) lg = -valB;
        ss += 16;
      } else {
        int sl = ss + g8; if (sl >= cnt) sl = cnt - 1;
        int j = __shfl(jj, sl);
        uint4 vv = P4[(size_t)j * 8 + lane8];
        float p = logit8(vv);
        p += __shfl_xor(p, 1, 8);
        p += __shfl_xor(p, 2, 8);
        p += __shfl_xor(p, 4, 8);
        float val = __shfl(p, capsrc);
        if (ss == capbase && lane < cnt) lg = -val;
        ss += 8;
      }
    }
    // ---- max (incl. rare deg>64 tail) ----
    float mx = lg;
    for (int s = b0 + 64; s < b1; ++s) {
      int j = srcj[s];
      float d = apl * (psl - __half2float(PS[(size_t)j * 64 + lane]));
      float p = d * d;
      for (int m = 32; m; m >>= 1) p += __shfl_xor(p, m);
      mx = fmaxf(mx, -p);
    }
    for (int m = 32; m; m >>= 1) mx = fmaxf(mx, __shfl_xor(mx, m));
    // ---- exp-sum ----
    float ex = (lane < cnt) ? __expf(lg - mx) : 0.f;
    float sm = ex;
    for (int s = b0 + 64; s < b1; ++s) {
      int j = srcj[s];
      float d = apl * (psl - __half2float(PS[(size_t)j * 64 + lane]));
      float p = d * d;
      for (int m = 32; m; m >>= 1) p += __shfl_xor(p, m);
      if (lane == 0) sm += __expf(-p - mx);
    }
    for (int m = 32; m; m >>= 1) sm += __shfl_xor(sm, m);
    float inv = 1.0f / (sm + 1e-16f);
    float w = ex * inv;
    // ---- weighted RAW aggregation: 16 gathers in flight ----
    float acc = 0.f;
    ss = 0;
    for (; ss + 16 <= cnt; ss += 16) {
      int jv[16]; float wv[16];
#pragma unroll
      for (int q = 0; q < 16; ++q) { jv[q] = __shfl(jj, ss + q); wv[q] = __shfl(w, ss + q); }
      float vv[16];
#pragma unroll
      for (int q = 0; q < 16; ++q) vv[q] = bf2f(UB[(size_t)jv[q] * 64 + lane]);
#pragma unroll
      for (int q = 0; q < 16; ++q) acc += wv[q] * vv[q];
    }
    for (; ss + 8 <= cnt; ss += 8) {
      int jv[8]; float wv[8];
#pragma unroll
      for (int q = 0; q < 8; ++q) { jv[q] = __shfl(jj, ss + q); wv[q] = __shfl(w, ss + q); }
      float vv[8];
#pragma unroll
      for (int q = 0; q < 8; ++q) vv[q] = bf2f(UB[(size_t)jv[q] * 64 + lane]);
#pragma unroll
      for (int q = 0; q < 8; ++q) acc += wv[q] * vv[q];
    }
    for (; ss < cnt; ++ss) {
      int j0 = __shfl(jj, ss);
      float w0 = __shfl(w, ss);
      acc += w0 * bf2f(UB[(size_t)j0 * 64 + lane]);
    }
    for (int s = b0 + 64; s < b1; ++s) {
      int j = srcj[s];
      float d = apl * (psl - __half2float(PS[(size_t)j * 64 + lane]));
      float p = d * d;
      for (int m = 32; m; m >>= 1) p += __shfl_xor(p, m);
      acc += __expf(-p - mx) * inv * bf2f(UB[(size_t)j * 64 + lane]);
    }
    aggv = au[lane] * acc + bue[lane];
  }
  float z = au[lane] * bf2f(UB[(size_t)node * 64 + lane]) + bue[lane];
  zma[wid][lane] = z - aggv;
  float h = aggv;
#pragma unroll 8
  for (int k = 0; k < 64; ++k) h += zma[wid][k] * mS[k * 64 + lane];
  HB[(size_t)node * 64 + lane] = f2bf(h);
}

// ---------- final BN + leaky: bf16 raw -> f32 out ----------
__global__ __launch_bounds__(256) void k_bnact16(const u16* __restrict__ raw, const float* __restrict__ af,
                                                 const float* __restrict__ bfp, float* __restrict__ out, int n8) {
  int i = blockIdx.x * 256 + threadIdx.x;
  int stride = gridDim.x * 256;
  for (; i < n8; i += stride) {
    int c0 = (i & 31) * 8;
    float av[8], bv[8];
    *(float4*)(av) = *(const float4*)(af + c0);  *(float4*)(av + 4) = *(const float4*)(af + c0 + 4);
    *(float4*)(bv) = *(const float4*)(bfp + c0); *(float4*)(bv + 4) = *(const float4*)(bfp + c0 + 4);
    u16x8 r = ((const u16x8*)raw)[i];
    float o[8];
#pragma unroll
    for (int j = 0; j < 8; ++j) {
      float v = bf2f((u16)r[j]) * av[j] + bv[j];
      o[j] = (v > 0.f) ? v : 0.01f * v;
    }
    ((float4*)out)[i * 2]     = *(float4*)(o);
    ((float4*)out)[i * 2 + 1] = *(float4*)(o + 4);
  }
}

extern "C" void kernel_launch(void* const* d_in, const int* in_sizes, int n_in,
                              void* d_out, int out_size, void* d_ws, size_t ws_size,
                              hipStream_t stream) {
  const float* x    = (const float*)d_in[0];
  const float* y    = (const float*)d_in[1];
  const int*   eidx = (const int*)d_in[3];
  const float* Wu   = (const float*)d_in[4];
  const float* gu   = (const float*)d_in[5];
  const float* bu   = (const float*)d_in[6];
  const float* Wp   = (const float*)d_in[7];
  const float* gp   = (const float*)d_in[8];
  const float* bp   = (const float*)d_in[9];
  const float* cIn  = (const float*)d_in[10];
  const float* Wm   = (const float*)d_in[11];
  const float* gm   = (const float*)d_in[12];
  const float* bm   = (const float*)d_in[13];
  const float* Wf   = (const float*)d_in[14];
  const float* gf   = (const float*)d_in[15];
  const float* bfv  = (const float*)d_in[16];

  const int N = in_sizes[0] / 256;
  const int E = in_sizes[3] / 2;
  const int* ei = eidx;
  const int* ej = eidx + E;

  char* ws = (char*)d_ws;
  float* MINV  = (float*)(ws + OFF_MINV);
  float* AU    = (float*)(ws + OFF_AU);
  float* BUE   = (float*)(ws + OFF_BUE);
  float* AP    = (float*)(ws + OFF_AP);
  float* APBE  = (float*)(ws + OFF_APBE);
  float* AM    = (float*)(ws + OFF_AM);
  float* BM    = (float*)(ws + OFF_BM);
  float* AF    = (float*)(ws + OFF_AF);
  float* BF    = (float*)(ws + OFF_BF);
  int*   BTOT  = (int*)(ws + OFF_BTOT);
  int*   BOFF  = (int*)(ws + OFF_BOFF);
  u16*   WUT   = (u16*)(ws + OFF_WUT);
  u16*   WMT   = (u16*)(ws + OFF_WMT);
  u16*   WFT   = (u16*)(ws + OFF_WFT);
  u16*   WPH   = (u16*)(ws + OFF_WPH);
  float* PART1A= (float*)(ws + OFF_PART1A);
  float* PART1B= (float*)(ws + OFF_PART1B);
  float* PART2A= (float*)(ws + OFF_PART2A);
  float* PART2B= (float*)(ws + OFF_PART2B);
  int*   ROWPTR= (int*)(ws + OFF_ROWPTR);
  int*   BLKCNT= (int*)(ws + OFF_BLKCNT);
  int*   BLKOFF= (int*)(ws + OFF_BLKOFF);
  u16*   HB    = (u16*)(ws + OFF_BLKCNT);    // reuse (BLKCNT/BLKOFF dead after kA3)
  int*   SRCJ  = (int*)(ws + OFF_SRCJ);
  u16*   RAWO  = (u16*)(ws + OFF_SRCJ);      // reuse (SRCJ dead after k_nodeall)
  u16*   UBRAW = (u16*)(ws + OFF_U);
  unsigned* TMP= (unsigned*)(ws + OFF_P);    // packed bins; dead after kB
  __half* PS   = (__half*)(ws + OFF_PS);     // raw su f16
  u16*   H2    = (u16*)(ws + OFF_H2);

  const float invN = 1.0f / (float)N;
  const int mtiles   = (N + 127) / 128;
  const int n8_256   = N * 256 / 8;
  const int nbk      = (N + 255) >> 8;
  const int chunk    = (E + NBLK_BIN - 1) / NBLK_BIN;

  k_tcvt_prep<<<705, 256, 0, stream>>>(Wu, Wm, Wf, Wp, WUT, WMT, WFT, WPH, cIn, MINV);

  // CSR build (no global atomics; counts preserved for kA3)
  kA1<<<NBLK_BIN, 256, 0, stream>>>(ei, E, chunk, BLKCNT, nbk);
  kA2<<<nbk, 256, 0, stream>>>(BLKCNT, nbk, BLKOFF, BTOT);
  kA2b<<<1, 512, 0, stream>>>(BTOT, BOFF, nbk);
  kA3<<<NBLK_BIN, 256, 0, stream>>>(ei, ej, E, chunk, BLKCNT, BLKOFF, BOFF, nbk, TMP);
  kB<<<nbk, 256, 0, stream>>>(TMP, BOFF, nbk, N, E, ROWPTR, SRCJ);

  // unary embedding (bf16 MFMA, stats fused) -> UBRAW
  k_mfma<64, 2, 1, 1, 0><<<dim3(mtiles, 1), 256, 0, stream>>>(
      nullptr, x, 256, 256, N, WUT, nullptr, UBRAW, 64, 64, PART1A, PART2A);

  // pairwise embedding (f16 MFMA, stats fused) -> raw su f16 directly
  k_mfma<64, 2, 2, 1, 1><<<dim3(mtiles, 1), 256, 0, stream>>>(
      nullptr, y, 256, 256, N, WPH, nullptr, (u16*)PS, 64, 64, PART1B, PART2B);

  // merged BN reduce for xu + su
  k_reduce2<<<128, 256, 0, stream>>>(PART1A, PART2A, PART1B, PART2B, mtiles, invN,
                                     gu, bu, gp, bp, AU, BUE, AP, APBE);

  // fused logits(ap in-reg) + softmax + aggregation + BN + CRF solve -> HB
  k_nodeall<<<(N + 3) / 4, 256, 0, stream>>>(PS, SRCJ, ROWPTR, UBRAW, AU, BUE, AP, MINV, N, HB);

  // h @ Wm -> h2 bf16
  k_mfma2<0><<<mtiles, 512, 0, stream>>>(
      HB, 64, 64, N, nullptr, nullptr, nullptr, nullptr, WMT, H2, PART1A, PART2A);
  k_reduce_fin<<<256, 256, 0, stream>>>(PART1A, PART2A, mtiles, 256, invN, gm, bm, AM, BM);

  // [leaky(bn(h2)), y] @ Wf -> raw bf16, BN + leaky -> d_out
  k_mfma2<1><<<mtiles, 512, 0, stream>>>(
      nullptr, 0, 512, N, H2, y, AM, BM, WFT, RAWO, PART1A, PART2A);
  k_reduce_fin<<<256, 256, 0, stream>>>(PART1A, PART2A, mtiles, 256, invN, gf, bfv, AF, BF);
  k_bnact16<<<2048, 256, 0, stream>>>(RAWO, AF, BF, (float*)d_out, n8_256);
}

// Round 14
// 514.523 us; speedup vs baseline: 1.0688x; 1.0688x over previous
//
#include <hip/hip_runtime.h>
#include <hip/hip_fp16.h>
#include <math.h>

typedef unsigned short u16;
typedef short s16x8 __attribute__((ext_vector_type(8)));
typedef unsigned short u16x8 __attribute__((ext_vector_type(8)));
typedef _Float16 f16x8 __attribute__((ext_vector_type(8)));
typedef float f32x4 __attribute__((ext_vector_type(4)));

// ---------- helpers ----------
__device__ __forceinline__ float bf2f(u16 u) {
  unsigned x = ((unsigned)u) << 16;
  return __uint_as_float(x);
}
__device__ __forceinline__ u16 f2bf(float f) {
  unsigned x = __float_as_uint(f);
  unsigned r = x + 0x7FFFu + ((x >> 16) & 1u);
  return (u16)(r >> 16);
}
__device__ __forceinline__ u16 f2h(float f) {
  __half h = __float2half_rn(f);
  return *reinterpret_cast<u16*>(&h);
}

// ---------- ws layout (bytes) ----------
static const size_t OFF_MINV   = 0;
static const size_t OFF_AU     = 32ull * 1024;
static const size_t OFF_BUE    = 32ull * 1024 + 256;
static const size_t OFF_AP     = 32ull * 1024 + 512;
static const size_t OFF_APBE   = 32ull * 1024 + 768;
static const size_t OFF_AM     = 36ull * 1024;
static const size_t OFF_BM     = 37ull * 1024;
static const size_t OFF_AF     = 38ull * 1024;
static const size_t OFF_BF     = 39ull * 1024;
static const size_t OFF_BTOT   = 40ull * 1024;
static const size_t OFF_BOFF   = 44ull * 1024;
static const size_t OFF_WUT    = 64ull * 1024;
static const size_t OFF_WMT    = 128ull * 1024;
static const size_t OFF_WFT    = 192ull * 1024;
static const size_t OFF_WPH    = 512ull * 1024;            // Wp^T f16 [64][256]
static const size_t OFF_PART1A = 1ull  * 1024 * 1024;
static const size_t OFF_PART1B = 1ull  * 1024 * 1024 + 512 * 1024;
static const size_t OFF_PART2A = 2ull  * 1024 * 1024;
static const size_t OFF_PART2B = 2ull  * 1024 * 1024 + 512 * 1024;
static const size_t OFF_ROWPTR = 3ull  * 1024 * 1024;
static const size_t OFF_BLKCNT = 5ull  * 1024 * 1024;     // counts 2MB; HB bf16 reuses 5..17.8MB later
static const size_t OFF_BLKOFF = 7ull  * 1024 * 1024;     // offsets 2MB (dead after kA3)
static const size_t OFF_SRCJ   = 18ull * 1024 * 1024;     // E int; dead after k_nodeall -> RAWO bf16 N*256
static const size_t OFF_U      = 44ull * 1024 * 1024;     // UBRAW bf16 N*64
static const size_t OFF_P      = 70ull * 1024 * 1024;     // TMP uint E (dead after kB)
static const size_t OFF_PS     = 109ull * 1024 * 1024;    // su f16 N*64 (raw, then ap-scaled in place)
static const size_t OFF_H2     = 122ull * 1024 * 1024;

#define NBLK_BIN 1024

// ---------- merged: weight transpose/convert (blocks 0..703) + Minv prep (block 704) ----------
__global__ __launch_bounds__(256) void k_tcvt_prep(const float* __restrict__ Wu, const float* __restrict__ Wm,
                                                   const float* __restrict__ Wf, const float* __restrict__ Wp,
                                                   u16* __restrict__ WUT, u16* __restrict__ WMT,
                                                   u16* __restrict__ WFT, u16* __restrict__ WPH,
                                                   const float* __restrict__ c, float* __restrict__ minv_out) {
  int b = blockIdx.x, t = threadIdx.x;
  if (b < 64) {
    int i = b * 256 + t;
    int k = i >> 6, n = i & 63;
    WUT[(size_t)n * 256 + k] = f2bf(Wu[i]);
    return;
  } else if (b < 128) {
    int i = (b - 64) * 256 + t;
    int k = i >> 8, n = i & 255;
    WMT[(size_t)n * 64 + k] = f2bf(Wm[i]);
    return;
  } else if (b < 640) {
    int i = (b - 128) * 256 + t;
    int k = i >> 8, n = i & 255;
    WFT[(size_t)n * 512 + k] = f2bf(Wf[i]);
    return;
  } else if (b < 704) {
    int i = (b - 640) * 256 + t;
    int k = i >> 6, n = i & 63;
    WPH[(size_t)n * 256 + k] = f2h(Wp[i]);
    return;
  }
  // ---- block 704: Minv = (I + c^T c)^-1 (conflict-free GJ, deferred normalization) ----
  __shared__ float CC[4096];
  __shared__ float aug[64 * 129];
  __shared__ float fs[64];
  float* cl = aug;
  for (int idx = t; idx < 4096; idx += 256) cl[idx] = c[idx];
  __syncthreads();
  for (int idx = t; idx < 4096; idx += 256) {
    int a = idx >> 6, bb = idx & 63;
    float s = (a == bb) ? 1.f : 0.f;
    for (int k = 0; k < 64; ++k) s += cl[k * 64 + a] * cl[k * 64 + bb];
    CC[idx] = s;
  }
  __syncthreads();
  for (int idx = t; idx < 8192; idx += 256) {
    int r = idx >> 7, cc = idx & 127;
    aug[r * 129 + cc] = (cc < 64) ? CC[r * 64 + cc] : (((cc - 64) == r) ? 1.f : 0.f);
  }
  __syncthreads();
  int cloc = t & 127;
  int rbase = t >> 7;
  for (int p = 0; p < 64; ++p) {
    if (t < 64) fs[t] = (t == p) ? 0.f : aug[t * 129 + p] / aug[p * 129 + p];
    __syncthreads();
    float pc = aug[p * 129 + cloc];
#pragma unroll
    for (int rr = 0; rr < 64; rr += 2) {
      int r = rr + rbase;
      aug[r * 129 + cloc] -= fs[r] * pc;
    }
    __syncthreads();
  }
  for (int idx = t; idx < 4096; idx += 256) {
    int r = idx >> 6, cc = idx & 63;
    minv_out[idx] = aug[r * 129 + 64 + cc] / aug[r * 129 + r];
  }
}

// ---------- binned CSR build ----------
__global__ __launch_bounds__(256) void kA1(const int* __restrict__ ei, int E, int chunk,
                                           int* __restrict__ blockCnt, int nbk) {
  __shared__ int c[512];
  int t = threadIdx.x, bid = blockIdx.x;
  c[t] = 0; c[t + 256] = 0;
  __syncthreads();
  int e0 = bid * chunk, e1 = min(E, e0 + chunk);
  for (int e = e0 + t; e < e1; e += 256) atomicAdd(&c[ei[e] >> 8], 1);
  __syncthreads();
  for (int b = t; b < nbk; b += 256) blockCnt[(size_t)bid * nbk + b] = c[b];
}

// kA2: per-bucket exclusive scan over blocks; counts preserved, offsets to blkOff
__global__ __launch_bounds__(256) void kA2(const int* __restrict__ blockCnt, int nbk,
                                           int* __restrict__ blkOff, int* __restrict__ bucketTot) {
  int b = blockIdx.x, t = threadIdx.x;
  int base = t * 4;
  int v0 = blockCnt[(size_t)(base + 0) * nbk + b];
  int v1 = blockCnt[(size_t)(base + 1) * nbk + b];
  int v2 = blockCnt[(size_t)(base + 2) * nbk + b];
  int v3 = blockCnt[(size_t)(base + 3) * nbk + b];
  int s1 = v0 + v1, s2 = s1 + v2, tot = s2 + v3;
  __shared__ int ps[256];
  ps[t] = tot;
  __syncthreads();
  for (int off = 1; off < 256; off <<= 1) {
    int a = (t >= off) ? ps[t - off] : 0;
    __syncthreads();
    ps[t] += a;
    __syncthreads();
  }
  int ex = (t > 0) ? ps[t - 1] : 0;
  blkOff[(size_t)(base + 0) * nbk + b] = ex;
  blkOff[(size_t)(base + 1) * nbk + b] = ex + v0;
  blkOff[(size_t)(base + 2) * nbk + b] = ex + s1;
  blkOff[(size_t)(base + 3) * nbk + b] = ex + s2;
  if (t == 255) bucketTot[b] = ps[255];
}

__global__ __launch_bounds__(512) void kA2b(const int* __restrict__ bucketTot,
                                            int* __restrict__ bucketOff, int nbk) {
  __shared__ int s[512];
  int t = threadIdx.x;
  s[t] = (t < nbk) ? bucketTot[t] : 0;
  __syncthreads();
  for (int off = 1; off < 512; off <<= 1) {
    int a = (t >= off) ? s[t - off] : 0;
    __syncthreads();
    s[t] += a;
    __syncthreads();
  }
  if (t == 0) bucketOff[0] = 0;
  if (t < nbk) bucketOff[t + 1] = s[t];
}

// A3: reload counts (no re-histogram), LDS counting-sort, packed 4B runs to TMP
__global__ __launch_bounds__(256) void kA3(const int* __restrict__ ei, const int* __restrict__ ej,
                                           int E, int chunk,
                                           const int* __restrict__ blockCnt,
                                           const int* __restrict__ blkOff,
                                           const int* __restrict__ bucketOff,
                                           int nbk, unsigned* __restrict__ tmp) {
  __shared__ int off[512], gb[512], cur[512];
  __shared__ uint2 stage[4096];
  int t = threadIdx.x, bid = blockIdx.x;
  int v0 = (t < nbk) ? blockCnt[(size_t)bid * nbk + t] : 0;
  int v1 = (t + 256 < nbk) ? blockCnt[(size_t)bid * nbk + t + 256] : 0;
  off[t] = v0; off[t + 256] = v1;
  __syncthreads();
  for (int o = 1; o < 512; o <<= 1) {
    int a0 = (t >= o) ? off[t - o] : 0;
    int a1 = ((t + 256) >= o) ? off[t + 256 - o] : 0;
    __syncthreads();
    off[t] += a0; off[t + 256] += a1;
    __syncthreads();
  }
  int ex0 = off[t] - v0, ex1 = off[t + 256] - v1;
  if (t < nbk)
    gb[t] = bucketOff[t] + blkOff[(size_t)bid * nbk + t] - ex0;
  if (t + 256 < nbk)
    gb[t + 256] = bucketOff[t + 256] + blkOff[(size_t)bid * nbk + t + 256] - ex1;
  cur[t] = ex0; cur[t + 256] = ex1;
  __syncthreads();
  int e0 = bid * chunk, e1 = min(E, e0 + chunk);
  int m = e1 - e0;
  for (int e = e0 + t; e < e1; e += 256) {
    int i = ei[e];
    int p = atomicAdd(&cur[i >> 8], 1);
    stage[p] = make_uint2((unsigned)i, (unsigned)ej[e]);
  }
  __syncthreads();
  for (int s = t; s < m; s += 256) {
    uint2 v = stage[s];
    tmp[gb[v.x >> 8] + s] = ((v.x & 255u) << 24) | v.y;
  }
}

#define BCAP 12288
__global__ __launch_bounds__(256) void kB(const unsigned* __restrict__ tmp,
                                          const int* __restrict__ bucketOff,
                                          int nbk, int N, int E,
                                          int* __restrict__ rowptr, int* __restrict__ srcj) {
  __shared__ int cnt[256], sc[256], cur[256];
  __shared__ int jbuf[BCAP];
  int b = blockIdx.x, t = threadIdx.x;
  int nb0 = b << 8;
  int e0 = bucketOff[b], e1 = bucketOff[b + 1];
  int m = e1 - e0;
  cnt[t] = 0;
  __syncthreads();
  for (int s = t; s < m; s += 256) atomicAdd(&cnt[tmp[e0 + s] >> 24], 1);
  __syncthreads();
  int v = cnt[t];
  sc[t] = v;
  __syncthreads();
  for (int off = 1; off < 256; off <<= 1) {
    int a = (t >= off) ? sc[t - off] : 0;
    __syncthreads();
    sc[t] += a;
    __syncthreads();
  }
  int exc = sc[t] - v;
  cur[t] = exc;
  if (nb0 + t < N) rowptr[nb0 + t] = e0 + exc;
  if (b == nbk - 1 && t == 0) rowptr[N] = E;
  __syncthreads();
  for (int s = t; s < m; s += 256) {
    unsigned e = tmp[e0 + s];
    int p = atomicAdd(&cur[e >> 24], 1);
    if (p < BCAP) jbuf[p] = (int)(e & 0xFFFFFFu);
  }
  __syncthreads();
  for (int s = t; s < m; s += 256) srcj[e0 + s] = jbuf[s];
}

// ---------- MFMA GEMM BM=128 x BN=64 (skinny paths) ----------
// AMODE 0: A bf16. AMODE 2: A f32 converted in staging. OBF: 0 f32, 1 bf16, 2 f16 out.
template<int BN, int AMODE, int OBF, int STATS, int FP16>
__global__ __launch_bounds__(256) void k_mfma(const u16* __restrict__ Abf, const float* __restrict__ Af32,
                                              int ldA, int K, int M,
                                              const u16* __restrict__ Bt,
                                              float* __restrict__ Cf, u16* __restrict__ Cb, int ldC,
                                              int ncTot, float* __restrict__ p1, float* __restrict__ p2) {
  constexpr int WN  = BN / 2;
  constexpr int FN  = WN / 16;
  constexpr int NPB = BN / 32;
  __shared__ u16 lds[2][(128 + BN) * 64];

  int t = threadIdx.x;
  int wid = t >> 6, lane = t & 63;
  int wr = wid >> 1, wc = wid & 1;
  int lr = lane & 15, lk = lane >> 4;
  int m0 = blockIdx.x * 128;
  int n0 = blockIdx.y * BN;
  int nK = K >> 6;

  int sidx = t;
  u16x8 ra[4];
  u16x8 rb[NPB];

  f32x4 acc[4][FN];
#pragma unroll
  for (int m = 0; m < 4; ++m)
#pragma unroll
    for (int n = 0; n < FN; ++n) acc[m][n] = (f32x4){0.f, 0.f, 0.f, 0.f};

  auto loadTile = [&](int kk) {
    int kk0 = kk * 64;
#pragma unroll
    for (int p = 0; p < 4; ++p) {
      int idx = p * 256 + sidx;
      int r = idx >> 3, c8 = idx & 7;
      int row = m0 + r; if (row >= M) row = M - 1;
      int k = kk0 + c8 * 8;
      if constexpr (AMODE == 0) {
        ra[p] = *(const u16x8*)(Abf + (size_t)row * ldA + k);
      } else {
        const float* src = Af32 + (size_t)row * ldA + k;
        float4 a = *(const float4*)src;
        float4 b = *(const float4*)(src + 4);
        u16x8 o;
        if constexpr (FP16) {
          o[0] = f2h(a.x); o[1] = f2h(a.y); o[2] = f2h(a.z); o[3] = f2h(a.w);
          o[4] = f2h(b.x); o[5] = f2h(b.y); o[6] = f2h(b.z); o[7] = f2h(b.w);
        } else {
          o[0] = f2bf(a.x); o[1] = f2bf(a.y); o[2] = f2bf(a.z); o[3] = f2bf(a.w);
          o[4] = f2bf(b.x); o[5] = f2bf(b.y); o[6] = f2bf(b.z); o[7] = f2bf(b.w);
        }
        ra[p] = o;
      }
    }
#pragma unroll
    for (int p = 0; p < NPB; ++p) {
      int idx = p * 256 + sidx;
      int r = idx >> 3, c8 = idx & 7;
      rb[p] = *(const u16x8*)(Bt + (size_t)(n0 + r) * K + kk0 + c8 * 8);
    }
  };

  auto dswrite = [&](int b) {
    char* As  = (char*)&lds[b][0];
    char* Bsc = As + 128 * 64 * 2;
#pragma unroll
    for (int p = 0; p < 4; ++p) {
      int idx = p * 256 + sidx;
      int r = idx >> 3, c8 = idx & 7;
      *(u16x8*)(As + r * 128 + ((c8 * 16) ^ ((r & 7) << 4))) = ra[p];
    }
#pragma unroll
    for (int p = 0; p < NPB; ++p) {
      int idx = p * 256 + sidx;
      int r = idx >> 3, c8 = idx & 7;
      *(u16x8*)(Bsc + r * 128 + ((c8 * 16) ^ ((r & 7) << 4))) = rb[p];
    }
  };

  auto compute = [&](int b) {
    const char* As  = (const char*)&lds[b][0];
    const char* Bsc = As + 128 * 64 * 2;
#pragma unroll
    for (int ks = 0; ks < 2; ++ks) {
      int kb = ks * 64 + lk * 16;
#pragma unroll
      for (int m = 0; m < 4; ++m) {
        int rowA = wr * 64 + m * 16 + lr;
        const char* pa = As + rowA * 128 + (kb ^ ((rowA & 7) << 4));
#pragma unroll
        for (int n = 0; n < FN; ++n) {
          int rowB = wc * WN + n * 16 + lr;
          const char* pb = Bsc + rowB * 128 + (kb ^ ((rowB & 7) << 4));
          if constexpr (FP16) {
            f16x8 af = *(const f16x8*)pa;
            f16x8 bf = *(const f16x8*)pb;
            acc[m][n] = __builtin_amdgcn_mfma_f32_16x16x32_f16(af, bf, acc[m][n], 0, 0, 0);
          } else {
            s16x8 af = *(const s16x8*)pa;
            s16x8 bf = *(const s16x8*)pb;
            acc[m][n] = __builtin_amdgcn_mfma_f32_16x16x32_bf16(af, bf, acc[m][n], 0, 0, 0);
          }
        }
      }
    }
  };

  loadTile(0);
  dswrite(0);
  __syncthreads();
  for (int kk = 0; kk < nK; ++kk) {
    int b = kk & 1;
    if (kk + 1 < nK) loadTile(kk + 1);
    compute(b);
    if (kk + 1 < nK) { dswrite(b ^ 1); __syncthreads(); }
  }

#pragma unroll
  for (int m = 0; m < 4; ++m) {
#pragma unroll
    for (int n = 0; n < FN; ++n) {
      int col = n0 + wc * WN + n * 16 + lr;
#pragma unroll
      for (int q = 0; q < 4; ++q) {
        int row = m0 + wr * 64 + m * 16 + lk * 4 + q;
        if (row < M) {
          if constexpr (OBF == 2)      Cb[(size_t)row * ldC + col] = f2h(acc[m][n][q]);
          else if constexpr (OBF == 1) Cb[(size_t)row * ldC + col] = f2bf(acc[m][n][q]);
          else                         Cf[(size_t)row * ldC + col] = acc[m][n][q];
        }
      }
    }
  }

  if constexpr (STATS) {
    __syncthreads();
    float* sb = (float*)&lds[0][0];
#pragma unroll
    for (int n = 0; n < FN; ++n) {
      float s1 = 0.f, s2 = 0.f;
#pragma unroll
      for (int m = 0; m < 4; ++m)
#pragma unroll
        for (int q = 0; q < 4; ++q) {
          int row = m0 + wr * 64 + m * 16 + lk * 4 + q;
          float v = (row < M) ? acc[m][n][q] : 0.f;
          s1 += v; s2 += v * v;
        }
      s1 += __shfl_xor(s1, 16); s2 += __shfl_xor(s2, 16);
      s1 += __shfl_xor(s1, 32); s2 += __shfl_xor(s2, 32);
      if (lk == 0) {
        int c = wc * WN + n * 16 + lr;
        sb[(wr * BN + c) * 2 + 0] = s1;
        sb[(wr * BN + c) * 2 + 1] = s2;
      }
    }
    __syncthreads();
    if (t < BN) {
      float s1 = sb[t * 2]     + sb[(BN + t) * 2];
      float s2 = sb[t * 2 + 1] + sb[(BN + t) * 2 + 1];
      p1[(size_t)blockIdx.x * ncTot + n0 + t] = s1;
      p2[(size_t)blockIdx.x * ncTot + n0 + t] = s2;
    }
  }
}

// ---------- MFMA GEMM2: BM=128 x BN=256, single-buffered LDS ----------
template<int AMODE>
__global__ __launch_bounds__(512) void k_mfma2(const u16* __restrict__ Abf, int ldA, int K, int M,
                                               const u16* __restrict__ h2, const float* __restrict__ yy,
                                               const float* __restrict__ am, const float* __restrict__ bm,
                                               const u16* __restrict__ Bt,
                                               u16* __restrict__ Cb,
                                               float* __restrict__ p1, float* __restrict__ p2) {
  __shared__ u16 lds[(128 + 256) * 64];
  int t = threadIdx.x;
  int wid = t >> 6, lane = t & 63;
  int wr = wid >> 2, wc = wid & 3;
  int lr = lane & 15, lk = lane >> 4;
  int m0 = blockIdx.x * 128;
  int nK = K >> 6;

  u16x8 ra[2];
  u16x8 rb[4];
  f32x4 acc[4][4];
#pragma unroll
  for (int m = 0; m < 4; ++m)
#pragma unroll
    for (int n = 0; n < 4; ++n) acc[m][n] = (f32x4){0.f, 0.f, 0.f, 0.f};

  auto loadTile = [&](int kk) {
    int kk0 = kk * 64;
#pragma unroll
    for (int p = 0; p < 2; ++p) {
      int idx = p * 512 + t;
      int r = idx >> 3, c8 = idx & 7;
      int row = m0 + r; if (row >= M) row = M - 1;
      int k = kk0 + c8 * 8;
      if constexpr (AMODE == 0) {
        ra[p] = *(const u16x8*)(Abf + (size_t)row * ldA + k);
      } else {
        if (kk0 < 256) {
          u16x8 h8 = *(const u16x8*)(h2 + (size_t)row * 256 + k);
          float av[8], bv[8];
          *(float4*)(av)     = *(const float4*)(am + k);
          *(float4*)(av + 4) = *(const float4*)(am + k + 4);
          *(float4*)(bv)     = *(const float4*)(bm + k);
          *(float4*)(bv + 4) = *(const float4*)(bm + k + 4);
          u16x8 o;
#pragma unroll
          for (int j = 0; j < 8; ++j) {
            float v = bf2f((u16)h8[j]) * av[j] + bv[j];
            v = v > 0.f ? v : 0.01f * v;
            o[j] = f2bf(v);
          }
          ra[p] = o;
        } else {
          float yv[8];
          *(float4*)(yv)     = *(const float4*)(yy + (size_t)row * 256 + (k - 256));
          *(float4*)(yv + 4) = *(const float4*)(yy + (size_t)row * 256 + (k - 256) + 4);
          u16x8 o;
#pragma unroll
          for (int j = 0; j < 8; ++j) o[j] = f2bf(yv[j]);
          ra[p] = o;
        }
      }
    }
#pragma unroll
    for (int p = 0; p < 4; ++p) {
      int idx = p * 512 + t;
      int r = idx >> 3, c8 = idx & 7;
      rb[p] = *(const u16x8*)(Bt + (size_t)r * K + kk0 + c8 * 8);
    }
  };

  auto dswrite = [&]() {
    char* As  = (char*)&lds[0];
    char* Bsc = As + 128 * 64 * 2;
#pragma unroll
    for (int p = 0; p < 2; ++p) {
      int idx = p * 512 + t;
      int r = idx >> 3, c8 = idx & 7;
      *(u16x8*)(As + r * 128 + ((c8 * 16) ^ ((r & 7) << 4))) = ra[p];
    }
#pragma unroll
    for (int p = 0; p < 4; ++p) {
      int idx = p * 512 + t;
      int r = idx >> 3, c8 = idx & 7;
      *(u16x8*)(Bsc + r * 128 + ((c8 * 16) ^ ((r & 7) << 4))) = rb[p];
    }
  };

  auto compute = [&]() {
    const char* As  = (const char*)&lds[0];
    const char* Bsc = As + 128 * 64 * 2;
#pragma unroll
    for (int ks = 0; ks < 2; ++ks) {
      int kb = ks * 64 + lk * 16;
      s16x8 af[4], bfr[4];
#pragma unroll
      for (int m = 0; m < 4; ++m) {
        int row = wr * 64 + m * 16 + lr;
        af[m] = *(const s16x8*)(As + row * 128 + (kb ^ ((row & 7) << 4)));
      }
#pragma unroll
      for (int n = 0; n < 4; ++n) {
        int row = wc * 64 + n * 16 + lr;
        bfr[n] = *(const s16x8*)(Bsc + row * 128 + (kb ^ ((row & 7) << 4)));
      }
#pragma unroll
      for (int m = 0; m < 4; ++m)
#pragma unroll
        for (int n = 0; n < 4; ++n)
          acc[m][n] = __builtin_amdgcn_mfma_f32_16x16x32_bf16(af[m], bfr[n], acc[m][n], 0, 0, 0);
    }
  };

  loadTile(0);
  for (int kk = 0; kk < nK; ++kk) {
    __syncthreads();
    dswrite();
    __syncthreads();
    if (kk + 1 < nK) loadTile(kk + 1);
    compute();
  }

#pragma unroll
  for (int m = 0; m < 4; ++m) {
#pragma unroll
    for (int n = 0; n < 4; ++n) {
      int col = wc * 64 + n * 16 + lr;
#pragma unroll
      for (int q = 0; q < 4; ++q) {
        int row = m0 + wr * 64 + m * 16 + lk * 4 + q;
        if (row < M) Cb[(size_t)row * 256 + col] = f2bf(acc[m][n][q]);
      }
    }
  }

  __syncthreads();
  float* sb = (float*)&lds[0];
#pragma unroll
  for (int n = 0; n < 4; ++n) {
    float s1 = 0.f, s2 = 0.f;
#pragma unroll
    for (int m = 0; m < 4; ++m)
#pragma unroll
      for (int q = 0; q < 4; ++q) {
        int row = m0 + wr * 64 + m * 16 + lk * 4 + q;
        float v = (row < M) ? acc[m][n][q] : 0.f;
        s1 += v; s2 += v * v;
      }
    s1 += __shfl_xor(s1, 16); s2 += __shfl_xor(s2, 16);
    s1 += __shfl_xor(s1, 32); s2 += __shfl_xor(s2, 32);
    if (lk == 0) {
      int c = wc * 64 + n * 16 + lr;
      sb[(wr * 256 + c) * 2 + 0] = s1;
      sb[(wr * 256 + c) * 2 + 1] = s2;
    }
  }
  __syncthreads();
  if (t < 256) {
    float s1 = sb[t * 2]     + sb[(256 + t) * 2];
    float s2 = sb[t * 2 + 1] + sb[(256 + t) * 2 + 1];
    p1[(size_t)blockIdx.x * 256 + t] = s1;
    p2[(size_t)blockIdx.x * 256 + t] = s2;
  }
}

// ---------- merged reduce: blocks 0-63 xu, 64-127 su ----------
__global__ __launch_bounds__(256) void k_reduce2(const float* __restrict__ p1a, const float* __restrict__ p2a,
                                                 const float* __restrict__ p1b, const float* __restrict__ p2b,
                                                 int nb, float invN,
                                                 const float* __restrict__ gu, const float* __restrict__ bu,
                                                 const float* __restrict__ gp, const float* __restrict__ bp,
                                                 float* __restrict__ AU, float* __restrict__ BUE,
                                                 float* __restrict__ AP, float* __restrict__ APBE) {
  int isB = blockIdx.x >> 6;
  int c = blockIdx.x & 63;
  int t = threadIdx.x;
  const float* part1 = isB ? p1b : p1a;
  const float* part2 = isB ? p2b : p2a;
  float s1 = 0.f, s2 = 0.f;
  for (int b = t; b < nb; b += 256) {
    s1 += part1[(size_t)b * 64 + c];
    s2 += part2[(size_t)b * 64 + c];
  }
  for (int m = 32; m; m >>= 1) { s1 += __shfl_xor(s1, m); s2 += __shfl_xor(s2, m); }
  __shared__ float l1[4], l2[4];
  if ((t & 63) == 0) { l1[t >> 6] = s1; l2[t >> 6] = s2; }
  __syncthreads();
  if (t == 0) {
    s1 = l1[0] + l1[1] + l1[2] + l1[3];
    s2 = l2[0] + l2[1] + l2[2] + l2[3];
    float mu  = s1 * invN;
    float var = s2 * invN - mu * mu;
    if (isB) {
      float a = gp[c] * rsqrtf(var + 1e-5f);
      AP[c] = a;
      APBE[c] = bp[c] - mu * a;
    } else {
      float a = gu[c] * rsqrtf(var + 1e-5f);
      AU[c] = a;
      BUE[c] = bu[c] - mu * a;
    }
  }
}

// ---------- reduce partials -> BN scale/shift (256 col) ----------
__global__ __launch_bounds__(256) void k_reduce_fin(const float* __restrict__ part1,
                                                    const float* __restrict__ part2,
                                                    int nb, int C, float invN,
                                                    const float* __restrict__ gamma,
                                                    const float* __restrict__ beta,
                                                    float* __restrict__ a_out,
                                                    float* __restrict__ b_out) {
  int c = blockIdx.x;
  int t = threadIdx.x;
  float s1 = 0.f, s2 = 0.f;
  for (int b = t; b < nb; b += 256) {
    s1 += part1[(size_t)b * C + c];
    s2 += part2[(size_t)b * C + c];
  }
  for (int m = 32; m; m >>= 1) { s1 += __shfl_xor(s1, m); s2 += __shfl_xor(s2, m); }
  __shared__ float l1[4], l2[4];
  if ((t & 63) == 0) { l1[t >> 6] = s1; l2[t >> 6] = s2; }
  __syncthreads();
  if (t == 0) {
    s1 = l1[0] + l1[1] + l1[2] + l1[3];
    s2 = l2[0] + l2[1] + l2[2] + l2[3];
    float mu  = s1 * invN;
    float var = s2 * invN - mu * mu;
    float a = gamma[c] * rsqrtf(var + 1e-5f);
    a_out[c] = a;
    b_out[c] = beta[c] - mu * a;
  }
}

// ---------- PS scale in place: PS = f16(ap * PS_raw) (PS rewritten each call: replay-safe) ----------
__global__ __launch_bounds__(256) void k_scaleP16(__half* __restrict__ PS, const float* __restrict__ ap, int n8) {
  for (int i = blockIdx.x * 256 + threadIdx.x; i < n8; i += gridDim.x * 256) {
    int c0 = (i & 7) * 8;
    float av[8];
    *(float4*)(av)     = *(const float4*)(ap + c0);
    *(float4*)(av + 4) = *(const float4*)(ap + c0 + 4);
    uint4 in = ((const uint4*)PS)[i];
    __half2* hp = (__half2*)&in;
    uint4 out;
    __half2* op = (__half2*)&out;
#pragma unroll
    for (int j = 0; j < 4; ++j) {
      float2 f = __half22float2(hp[j]);
      op[j] = __floats2half2_rn(f.x * av[j * 2], f.y * av[j * 2 + 1]);
    }
    ((uint4*)PS)[i] = out;
  }
}

// ---------- fused per-node: logits + softmax + RAW agg + BN + CRF solve (round-11 shape) ----------
__global__ __launch_bounds__(256) void k_nodeall(const __half* __restrict__ PS,
                                                 const int* __restrict__ srcj,
                                                 const int* __restrict__ rowptr,
                                                 const u16* __restrict__ UB,
                                                 const float* __restrict__ au,
                                                 const float* __restrict__ bue,
                                                 const float* __restrict__ minv,
                                                 int N, u16* __restrict__ HB) {
  __shared__ float mS[4096];
  __shared__ float zma[4][64];
  int t = threadIdx.x;
  for (int idx = t; idx < 1024; idx += 256)
    ((float4*)mS)[idx] = ((const float4*)minv)[idx];
  __syncthreads();

  int lane = t & 63, wid = t >> 6;
  int node = blockIdx.x * 4 + wid;
  if (node >= N) return;

  int lane8 = lane & 7, g8 = lane >> 3;
  const uint4* P4 = (const uint4*)PS;
  uint4 uv = P4[(size_t)node * 8 + lane8];
  float2 u0 = __half22float2(*(const __half2*)&uv.x);
  float2 u1 = __half22float2(((const __half2*)&uv.x)[1]);
  float2 u2 = __half22float2(*(const __half2*)&uv.z);
  float2 u3 = __half22float2(((const __half2*)&uv.z)[1]);
  float psl = __half2float(PS[(size_t)node * 64 + lane]);
  int b0 = rowptr[node], b1 = rowptr[node + 1];
  int deg = b1 - b0;
  float aggv = 0.f;
  if (deg > 0) {
    int cnt = deg < 64 ? deg : 64;
    int jj = (lane < cnt) ? srcj[b0 + lane] : 0;
    float lg = -INFINITY;
    int capbase = lane & ~7;
    int capsrc  = (lane & 7) << 3;
    for (int ss = 0; ss < cnt; ss += 8) {
      int sl = ss + g8; if (sl >= cnt) sl = cnt - 1;
      int j = __shfl(jj, sl);
      uint4 vv = P4[(size_t)j * 8 + lane8];
      float2 v0 = __half22float2(*(const __half2*)&vv.x);
      float2 v1 = __half22float2(((const __half2*)&vv.x)[1]);
      float2 v2 = __half22float2(*(const __half2*)&vv.z);
      float2 v3 = __half22float2(((const __half2*)&vv.z)[1]);
      float d0 = u0.x - v0.x, d1 = u0.y - v0.y;
      float d2 = u1.x - v1.x, d3 = u1.y - v1.y;
      float d4 = u2.x - v2.x, d5 = u2.y - v2.y;
      float d6 = u3.x - v3.x, d7 = u3.y - v3.y;
      float p = d0*d0 + d1*d1 + d2*d2 + d3*d3 + d4*d4 + d5*d5 + d6*d6 + d7*d7;
      p += __shfl_xor(p, 1, 8);
      p += __shfl_xor(p, 2, 8);
      p += __shfl_xor(p, 4, 8);
      float val = __shfl(p, capsrc);
      if (ss == capbase && lane < cnt) lg = -val;
    }
    float mx = lg;
    for (int s = b0 + 64; s < b1; ++s) {
      int j = srcj[s];
      float d = psl - __half2float(PS[(size_t)j * 64 + lane]);
      float p = d * d;
      for (int m = 32; m; m >>= 1) p += __shfl_xor(p, m);
      mx = fmaxf(mx, -p);
    }
    for (int m = 32; m; m >>= 1) mx = fmaxf(mx, __shfl_xor(mx, m));
    float ex = (lane < cnt) ? __expf(lg - mx) : 0.f;
    float sm = ex;
    for (int s = b0 + 64; s < b1; ++s) {
      int j = srcj[s];
      float d = psl - __half2float(PS[(size_t)j * 64 + lane]);
      float p = d * d;
      for (int m = 32; m; m >>= 1) p += __shfl_xor(p, m);
      if (lane == 0) sm += __expf(-p - mx);
    }
    for (int m = 32; m; m >>= 1) sm += __shfl_xor(sm, m);
    float inv = 1.0f / (sm + 1e-16f);
    float w = ex * inv;
    float acc = 0.f;
    int ss = 0;
    for (; ss + 8 <= cnt; ss += 8) {
      int   j0 = __shfl(jj, ss),     j1 = __shfl(jj, ss + 1);
      int   j2 = __shfl(jj, ss + 2), j3 = __shfl(jj, ss + 3);
      int   j4 = __shfl(jj, ss + 4), j5 = __shfl(jj, ss + 5);
      int   j6 = __shfl(jj, ss + 6), j7 = __shfl(jj, ss + 7);
      float w0 = __shfl(w, ss),      w1 = __shfl(w, ss + 1);
      float w2 = __shfl(w, ss + 2),  w3 = __shfl(w, ss + 3);
      float w4 = __shfl(w, ss + 4),  w5 = __shfl(w, ss + 5);
      float w6 = __shfl(w, ss + 6),  w7 = __shfl(w, ss + 7);
      float v0 = bf2f(UB[(size_t)j0 * 64 + lane]);
      float v1 = bf2f(UB[(size_t)j1 * 64 + lane]);
      float v2 = bf2f(UB[(size_t)j2 * 64 + lane]);
      float v3 = bf2f(UB[(size_t)j3 * 64 + lane]);
      float v4 = bf2f(UB[(size_t)j4 * 64 + lane]);
      float v5 = bf2f(UB[(size_t)j5 * 64 + lane]);
      float v6 = bf2f(UB[(size_t)j6 * 64 + lane]);
      float v7 = bf2f(UB[(size_t)j7 * 64 + lane]);
      acc += w0 * v0 + w1 * v1 + w2 * v2 + w3 * v3;
      acc += w4 * v4 + w5 * v5 + w6 * v6 + w7 * v7;
    }
    for (; ss < cnt; ++ss) {
      int j0 = __shfl(jj, ss);
      float w0 = __shfl(w, ss);
      acc += w0 * bf2f(UB[(size_t)j0 * 64 + lane]);
    }
    for (int s = b0 + 64; s < b1; ++s) {
      int j = srcj[s];
      float d = psl - __half2float(PS[(size_t)j * 64 + lane]);
      float p = d * d;
      for (int m = 32; m; m >>= 1) p += __shfl_xor(p, m);
      acc += __expf(-p - mx) * inv * bf2f(UB[(size_t)j * 64 + lane]);
    }
    aggv = au[lane] * acc + bue[lane];
  }
  float z = au[lane] * bf2f(UB[(size_t)node * 64 + lane]) + bue[lane];
  zma[wid][lane] = z - aggv;
  float h = aggv;
#pragma unroll 8
  for (int k = 0; k < 64; ++k) h += zma[wid][k] * mS[k * 64 + lane];
  HB[(size_t)node * 64 + lane] = f2bf(h);
}

// ---------- final BN + leaky: bf16 raw -> f32 out ----------
__global__ __launch_bounds__(256) void k_bnact16(const u16* __restrict__ raw, const float* __restrict__ af,
                                                 const float* __restrict__ bfp, float* __restrict__ out, int n8) {
  int i = blockIdx.x * 256 + threadIdx.x;
  int stride = gridDim.x * 256;
  for (; i < n8; i += stride) {
    int c0 = (i & 31) * 8;
    float av[8], bv[8];
    *(float4*)(av) = *(const float4*)(af + c0);  *(float4*)(av + 4) = *(const float4*)(af + c0 + 4);
    *(float4*)(bv) = *(const float4*)(bfp + c0); *(float4*)(bv + 4) = *(const float4*)(bfp + c0 + 4);
    u16x8 r = ((const u16x8*)raw)[i];
    float o[8];
#pragma unroll
    for (int j = 0; j < 8; ++j) {
      float v = bf2f((u16)r[j]) * av[j] + bv[j];
      o[j] = (v > 0.f) ? v : 0.01f * v;
    }
    ((float4*)out)[i * 2]     = *(float4*)(o);
    ((float4*)out)[i * 2 + 1] = *(float4*)(o + 4);
  }
}

extern "C" void kernel_launch(void* const* d_in, const int* in_sizes, int n_in,
                              void* d_out, int out_size, void* d_ws, size_t ws_size,
                              hipStream_t stream) {
  const float* x    = (const float*)d_in[0];
  const float* y    = (const float*)d_in[1];
  const int*   eidx = (const int*)d_in[3];
  const float* Wu   = (const float*)d_in[4];
  const float* gu   = (const float*)d_in[5];
  const float* bu   = (const float*)d_in[6];
  const float* Wp   = (const float*)d_in[7];
  const float* gp   = (const float*)d_in[8];
  const float* bp   = (const float*)d_in[9];
  const float* cIn  = (const float*)d_in[10];
  const float* Wm   = (const float*)d_in[11];
  const float* gm   = (const float*)d_in[12];
  const float* bm   = (const float*)d_in[13];
  const float* Wf   = (const float*)d_in[14];
  const float* gf   = (const float*)d_in[15];
  const float* bfv  = (const float*)d_in[16];

  const int N = in_sizes[0] / 256;
  const int E = in_sizes[3] / 2;
  const int* ei = eidx;
  const int* ej = eidx + E;

  char* ws = (char*)d_ws;
  float* MINV  = (float*)(ws + OFF_MINV);
  float* AU    = (float*)(ws + OFF_AU);
  float* BUE   = (float*)(ws + OFF_BUE);
  float* AP    = (float*)(ws + OFF_AP);
  float* APBE  = (float*)(ws + OFF_APBE);
  float* AM    = (float*)(ws + OFF_AM);
  float* BM    = (float*)(ws + OFF_BM);
  float* AF    = (float*)(ws + OFF_AF);
  float* BF    = (float*)(ws + OFF_BF);
  int*   BTOT  = (int*)(ws + OFF_BTOT);
  int*   BOFF  = (int*)(ws + OFF_BOFF);
  u16*   WUT   = (u16*)(ws + OFF_WUT);
  u16*   WMT   = (u16*)(ws + OFF_WMT);
  u16*   WFT   = (u16*)(ws + OFF_WFT);
  u16*   WPH   = (u16*)(ws + OFF_WPH);
  float* PART1A= (float*)(ws + OFF_PART1A);
  float* PART1B= (float*)(ws + OFF_PART1B);
  float* PART2A= (float*)(ws + OFF_PART2A);
  float* PART2B= (float*)(ws + OFF_PART2B);
  int*   ROWPTR= (int*)(ws + OFF_ROWPTR);
  int*   BLKCNT= (int*)(ws + OFF_BLKCNT);
  int*   BLKOFF= (int*)(ws + OFF_BLKOFF);
  u16*   HB    = (u16*)(ws + OFF_BLKCNT);    // reuse (BLKCNT/BLKOFF dead after kA3)
  int*   SRCJ  = (int*)(ws + OFF_SRCJ);
  u16*   RAWO  = (u16*)(ws + OFF_SRCJ);      // reuse (SRCJ dead after k_nodeall)
  u16*   UBRAW = (u16*)(ws + OFF_U);
  unsigned* TMP= (unsigned*)(ws + OFF_P);    // packed bins; dead after kB
  __half* PS   = (__half*)(ws + OFF_PS);     // su f16 (raw, then scaled in place)
  u16*   H2    = (u16*)(ws + OFF_H2);

  const float invN = 1.0f / (float)N;
  const int mtiles   = (N + 127) / 128;
  const int n8_64    = N * 64 / 8;
  const int n8_256   = N * 256 / 8;
  const int nbk      = (N + 255) >> 8;
  const int chunk    = (E + NBLK_BIN - 1) / NBLK_BIN;

  k_tcvt_prep<<<705, 256, 0, stream>>>(Wu, Wm, Wf, Wp, WUT, WMT, WFT, WPH, cIn, MINV);

  // CSR build (no global atomics; counts preserved for kA3)
  kA1<<<NBLK_BIN, 256, 0, stream>>>(ei, E, chunk, BLKCNT, nbk);
  kA2<<<nbk, 256, 0, stream>>>(BLKCNT, nbk, BLKOFF, BTOT);
  kA2b<<<1, 512, 0, stream>>>(BTOT, BOFF, nbk);
  kA3<<<NBLK_BIN, 256, 0, stream>>>(ei, ej, E, chunk, BLKCNT, BLKOFF, BOFF, nbk, TMP);
  kB<<<nbk, 256, 0, stream>>>(TMP, BOFF, nbk, N, E, ROWPTR, SRCJ);

  // unary embedding (bf16 MFMA, stats fused) -> UBRAW
  k_mfma<64, 2, 1, 1, 0><<<dim3(mtiles, 1), 256, 0, stream>>>(
      nullptr, x, 256, 256, N, WUT, nullptr, UBRAW, 64, 64, PART1A, PART2A);

  // pairwise embedding (f16 MFMA, stats fused) -> raw su f16
  k_mfma<64, 2, 2, 1, 1><<<dim3(mtiles, 1), 256, 0, stream>>>(
      nullptr, y, 256, 256, N, WPH, nullptr, (u16*)PS, 64, 64, PART1B, PART2B);

  // merged BN reduce for xu + su, then scale PS in place by ap
  k_reduce2<<<128, 256, 0, stream>>>(PART1A, PART2A, PART1B, PART2B, mtiles, invN,
                                     gu, bu, gp, bp, AU, BUE, AP, APBE);
  k_scaleP16<<<1024, 256, 0, stream>>>(PS, AP, n8_64);

  // fused logits + softmax + aggregation + BN + CRF solve -> HB
  k_nodeall<<<(N + 3) / 4, 256, 0, stream>>>(PS, SRCJ, ROWPTR, UBRAW, AU, BUE, MINV, N, HB);

  // h @ Wm -> h2 bf16
  k_mfma2<0><<<mtiles, 512, 0, stream>>>(
      HB, 64, 64, N, nullptr, nullptr, nullptr, nullptr, WMT, H2, PART1A, PART2A);
  k_reduce_fin<<<256, 256, 0, stream>>>(PART1A, PART2A, mtiles, 256, invN, gm, bm, AM, BM);

  // [leaky(bn(h2)), y] @ Wf -> raw bf16, BN + leaky -> d_out
  k_mfma2<1><<<mtiles, 512, 0, stream>>>(
      nullptr, 0, 512, N, H2, y, AM, BM, WFT, RAWO, PART1A, PART2A);
  k_reduce_fin<<<256, 256, 0, stream>>>(PART1A, PART2A, mtiles, 256, invN, gf, bfv, AF, BF);
  k_bnact16<<<2048, 256, 0, stream>>>(RAWO, AF, BF, (float*)d_out, n8_256);
}

// Round 15
// 508.351 us; speedup vs baseline: 1.0818x; 1.0121x over previous
//
#include <hip/hip_runtime.h>
#include <hip/hip_fp16.h>
#include <math.h>

typedef unsigned short u16;
typedef short s16x8 __attribute__((ext_vector_type(8)));
typedef unsigned short u16x8 __attribute__((ext_vector_type(8)));
typedef _Float16 f16x8 __attribute__((ext_vector_type(8)));
typedef float f32x4 __attribute__((ext_vector_type(4)));

// ---------- helpers ----------
__device__ __forceinline__ float bf2f(u16 u) {
  unsigned x = ((unsigned)u) << 16;
  return __uint_as_float(x);
}
__device__ __forceinline__ u16 f2bf(float f) {
  unsigned x = __float_as_uint(f);
  unsigned r = x + 0x7FFFu + ((x >> 16) & 1u);
  return (u16)(r >> 16);
}
__device__ __forceinline__ u16 f2h(float f) {
  __half h = __float2half_rn(f);
  return *reinterpret_cast<u16*>(&h);
}

// ---------- ws layout (bytes) ----------
static const size_t OFF_MINV   = 0;
static const size_t OFF_AU     = 32ull * 1024;
static const size_t OFF_BUE    = 32ull * 1024 + 256;
static const size_t OFF_AP     = 32ull * 1024 + 512;
static const size_t OFF_APBE   = 32ull * 1024 + 768;
static const size_t OFF_AM     = 36ull * 1024;
static const size_t OFF_BM     = 37ull * 1024;
static const size_t OFF_AF     = 38ull * 1024;
static const size_t OFF_BF     = 39ull * 1024;
static const size_t OFF_BTOT   = 40ull * 1024;
static const size_t OFF_BOFF   = 44ull * 1024;
static const size_t OFF_WUT    = 64ull * 1024;
static const size_t OFF_WMT    = 128ull * 1024;
static const size_t OFF_WFT    = 192ull * 1024;
static const size_t OFF_WPH    = 512ull * 1024;            // Wp^T f16 [64][256]
static const size_t OFF_PART1A = 1ull  * 1024 * 1024;
static const size_t OFF_PART1B = 1ull  * 1024 * 1024 + 512 * 1024;
static const size_t OFF_PART2A = 2ull  * 1024 * 1024;
static const size_t OFF_PART2B = 2ull  * 1024 * 1024 + 512 * 1024;
static const size_t OFF_ROWPTR = 3ull  * 1024 * 1024;
static const size_t OFF_BLKCNT = 5ull  * 1024 * 1024;     // counts 2MB; HB bf16 reuses 5..17.8MB later
static const size_t OFF_BLKOFF = 7ull  * 1024 * 1024;     // offsets 2MB (dead after kA3)
static const size_t OFF_SRCJ   = 18ull * 1024 * 1024;     // E int; dead after k_nodeall -> RAWO bf16 N*256
static const size_t OFF_U      = 44ull * 1024 * 1024;     // UBRAW bf16 N*64
static const size_t OFF_P      = 70ull * 1024 * 1024;     // TMP uint E (dead after kB)
static const size_t OFF_PS     = 109ull * 1024 * 1024;    // su f16 N*64 (raw, then ap-scaled in place)
static const size_t OFF_H2     = 122ull * 1024 * 1024;

#define NBLK_BIN 1024

// ---------- merged: weight transpose/convert (0..703) + Minv prep (704) + edge histogram (705..) ----------
__global__ __launch_bounds__(256) void k_tcvt_prep(const float* __restrict__ Wu, const float* __restrict__ Wm,
                                                   const float* __restrict__ Wf, const float* __restrict__ Wp,
                                                   u16* __restrict__ WUT, u16* __restrict__ WMT,
                                                   u16* __restrict__ WFT, u16* __restrict__ WPH,
                                                   const float* __restrict__ c, float* __restrict__ minv_out,
                                                   const int* __restrict__ ei, int E, int chunk,
                                                   int* __restrict__ blockCnt, int nbk) {
  __shared__ float CC[4096];
  __shared__ float aug[64 * 129];
  __shared__ float fs[64];
  int b = blockIdx.x, t = threadIdx.x;
  if (b < 64) {
    int i = b * 256 + t;
    int k = i >> 6, n = i & 63;
    WUT[(size_t)n * 256 + k] = f2bf(Wu[i]);
    return;
  } else if (b < 128) {
    int i = (b - 64) * 256 + t;
    int k = i >> 8, n = i & 255;
    WMT[(size_t)n * 64 + k] = f2bf(Wm[i]);
    return;
  } else if (b < 640) {
    int i = (b - 128) * 256 + t;
    int k = i >> 8, n = i & 255;
    WFT[(size_t)n * 512 + k] = f2bf(Wf[i]);
    return;
  } else if (b < 704) {
    int i = (b - 640) * 256 + t;
    int k = i >> 6, n = i & 63;
    WPH[(size_t)n * 256 + k] = f2h(Wp[i]);
    return;
  } else if (b >= 705) {
    // ---- histogram blocks (kA1): bucket = i>>8, LDS aliased into CC ----
    int* cnt = (int*)CC;
    int bid = b - 705;
    cnt[t] = 0; cnt[t + 256] = 0;
    __syncthreads();
    int e0 = bid * chunk, e1 = min(E, e0 + chunk);
    for (int e = e0 + t; e < e1; e += 256) atomicAdd(&cnt[ei[e] >> 8], 1);
    __syncthreads();
    for (int bb = t; bb < nbk; bb += 256) blockCnt[(size_t)bid * nbk + bb] = cnt[bb];
    return;
  }
  // ---- block 704: Minv = (I + c^T c)^-1 (conflict-free GJ, deferred normalization) ----
  float* cl = aug;
  for (int idx = t; idx < 4096; idx += 256) cl[idx] = c[idx];
  __syncthreads();
  for (int idx = t; idx < 4096; idx += 256) {
    int a = idx >> 6, bb = idx & 63;
    float s = (a == bb) ? 1.f : 0.f;
    for (int k = 0; k < 64; ++k) s += cl[k * 64 + a] * cl[k * 64 + bb];
    CC[idx] = s;
  }
  __syncthreads();
  for (int idx = t; idx < 8192; idx += 256) {
    int r = idx >> 7, cc = idx & 127;
    aug[r * 129 + cc] = (cc < 64) ? CC[r * 64 + cc] : (((cc - 64) == r) ? 1.f : 0.f);
  }
  __syncthreads();
  int cloc = t & 127;
  int rbase = t >> 7;
  for (int p = 0; p < 64; ++p) {
    if (t < 64) fs[t] = (t == p) ? 0.f : aug[t * 129 + p] / aug[p * 129 + p];
    __syncthreads();
    float pc = aug[p * 129 + cloc];
#pragma unroll
    for (int rr = 0; rr < 64; rr += 2) {
      int r = rr + rbase;
      aug[r * 129 + cloc] -= fs[r] * pc;
    }
    __syncthreads();
  }
  for (int idx = t; idx < 4096; idx += 256) {
    int r = idx >> 6, cc = idx & 63;
    minv_out[idx] = aug[r * 129 + 64 + cc] / aug[r * 129 + r];
  }
}

// kA2: per-bucket exclusive scan over blocks; counts preserved, offsets to blkOff
__global__ __launch_bounds__(256) void kA2(const int* __restrict__ blockCnt, int nbk,
                                           int* __restrict__ blkOff, int* __restrict__ bucketTot) {
  int b = blockIdx.x, t = threadIdx.x;
  int base = t * 4;
  int v0 = blockCnt[(size_t)(base + 0) * nbk + b];
  int v1 = blockCnt[(size_t)(base + 1) * nbk + b];
  int v2 = blockCnt[(size_t)(base + 2) * nbk + b];
  int v3 = blockCnt[(size_t)(base + 3) * nbk + b];
  int s1 = v0 + v1, s2 = s1 + v2, tot = s2 + v3;
  __shared__ int ps[256];
  ps[t] = tot;
  __syncthreads();
  for (int off = 1; off < 256; off <<= 1) {
    int a = (t >= off) ? ps[t - off] : 0;
    __syncthreads();
    ps[t] += a;
    __syncthreads();
  }
  int ex = (t > 0) ? ps[t - 1] : 0;
  blkOff[(size_t)(base + 0) * nbk + b] = ex;
  blkOff[(size_t)(base + 1) * nbk + b] = ex + v0;
  blkOff[(size_t)(base + 2) * nbk + b] = ex + s1;
  blkOff[(size_t)(base + 3) * nbk + b] = ex + s2;
  if (t == 255) bucketTot[b] = ps[255];
}

__global__ __launch_bounds__(512) void kA2b(const int* __restrict__ bucketTot,
                                            int* __restrict__ bucketOff, int nbk) {
  __shared__ int s[512];
  int t = threadIdx.x;
  s[t] = (t < nbk) ? bucketTot[t] : 0;
  __syncthreads();
  for (int off = 1; off < 512; off <<= 1) {
    int a = (t >= off) ? s[t - off] : 0;
    __syncthreads();
    s[t] += a;
    __syncthreads();
  }
  if (t == 0) bucketOff[0] = 0;
  if (t < nbk) bucketOff[t + 1] = s[t];
}

// A3: reload counts (no re-histogram), LDS counting-sort, packed 4B runs to TMP
__global__ __launch_bounds__(256) void kA3(const int* __restrict__ ei, const int* __restrict__ ej,
                                           int E, int chunk,
                                           const int* __restrict__ blockCnt,
                                           const int* __restrict__ blkOff,
                                           const int* __restrict__ bucketOff,
                                           int nbk, unsigned* __restrict__ tmp) {
  __shared__ int off[512], gb[512], cur[512];
  __shared__ uint2 stage[4096];
  int t = threadIdx.x, bid = blockIdx.x;
  int v0 = (t < nbk) ? blockCnt[(size_t)bid * nbk + t] : 0;
  int v1 = (t + 256 < nbk) ? blockCnt[(size_t)bid * nbk + t + 256] : 0;
  off[t] = v0; off[t + 256] = v1;
  __syncthreads();
  for (int o = 1; o < 512; o <<= 1) {
    int a0 = (t >= o) ? off[t - o] : 0;
    int a1 = ((t + 256) >= o) ? off[t + 256 - o] : 0;
    __syncthreads();
    off[t] += a0; off[t + 256] += a1;
    __syncthreads();
  }
  int ex0 = off[t] - v0, ex1 = off[t + 256] - v1;
  if (t < nbk)
    gb[t] = bucketOff[t] + blkOff[(size_t)bid * nbk + t] - ex0;
  if (t + 256 < nbk)
    gb[t + 256] = bucketOff[t + 256] + blkOff[(size_t)bid * nbk + t + 256] - ex1;
  cur[t] = ex0; cur[t + 256] = ex1;
  __syncthreads();
  int e0 = bid * chunk, e1 = min(E, e0 + chunk);
  int m = e1 - e0;
  for (int e = e0 + t; e < e1; e += 256) {
    int i = ei[e];
    int p = atomicAdd(&cur[i >> 8], 1);
    stage[p] = make_uint2((unsigned)i, (unsigned)ej[e]);
  }
  __syncthreads();
  for (int s = t; s < m; s += 256) {
    uint2 v = stage[s];
    tmp[gb[v.x >> 8] + s] = ((v.x & 255u) << 24) | v.y;
  }
}

#define BCAP 12288
__global__ __launch_bounds__(256) void kB(const unsigned* __restrict__ tmp,
                                          const int* __restrict__ bucketOff,
                                          int nbk, int N, int E,
                                          int* __restrict__ rowptr, int* __restrict__ srcj) {
  __shared__ int cnt[256], sc[256], cur[256];
  __shared__ int jbuf[BCAP];
  int b = blockIdx.x, t = threadIdx.x;
  int nb0 = b << 8;
  int e0 = bucketOff[b], e1 = bucketOff[b + 1];
  int m = e1 - e0;
  cnt[t] = 0;
  __syncthreads();
  for (int s = t; s < m; s += 256) atomicAdd(&cnt[tmp[e0 + s] >> 24], 1);
  __syncthreads();
  int v = cnt[t];
  sc[t] = v;
  __syncthreads();
  for (int off = 1; off < 256; off <<= 1) {
    int a = (t >= off) ? sc[t - off] : 0;
    __syncthreads();
    sc[t] += a;
    __syncthreads();
  }
  int exc = sc[t] - v;
  cur[t] = exc;
  if (nb0 + t < N) rowptr[nb0 + t] = e0 + exc;
  if (b == nbk - 1 && t == 0) rowptr[N] = E;
  __syncthreads();
  for (int s = t; s < m; s += 256) {
    unsigned e = tmp[e0 + s];
    int p = atomicAdd(&cur[e >> 24], 1);
    if (p < BCAP) jbuf[p] = (int)(e & 0xFFFFFFu);
  }
  __syncthreads();
  for (int s = t; s < m; s += 256) srcj[e0 + s] = jbuf[s];
}

// ---------- dual embedding GEMM: y-dim selects xu (bf16) or su (f16) path ----------
// BM=128, BN=64, K=256; A f32 converted in staging; stats fused.
__global__ __launch_bounds__(256) void k_gemm_em(const float* __restrict__ x, const float* __restrict__ yy,
                                                 const u16* __restrict__ WUT, const u16* __restrict__ WPH,
                                                 int M,
                                                 u16* __restrict__ UB, u16* __restrict__ PSo,
                                                 float* __restrict__ p1a, float* __restrict__ p2a,
                                                 float* __restrict__ p1b, float* __restrict__ p2b) {
  constexpr int BN = 64;
  __shared__ u16 lds[2][(128 + BN) * 64];
  const bool su = (blockIdx.y != 0);
  const float* Af32 = su ? yy : x;
  const u16* Bt = su ? WPH : WUT;
  const int K = 256;

  int t = threadIdx.x;
  int wid = t >> 6, lane = t & 63;
  int wr = wid >> 1, wc = wid & 1;
  int lr = lane & 15, lk = lane >> 4;
  int m0 = blockIdx.x * 128;
  int nK = K >> 6;

  u16x8 ra[4];
  u16x8 rb[2];
  f32x4 acc[4][2];
#pragma unroll
  for (int m = 0; m < 4; ++m)
#pragma unroll
    for (int n = 0; n < 2; ++n) acc[m][n] = (f32x4){0.f, 0.f, 0.f, 0.f};

  auto loadTile = [&](int kk) {
    int kk0 = kk * 64;
#pragma unroll
    for (int p = 0; p < 4; ++p) {
      int idx = p * 256 + t;
      int r = idx >> 3, c8 = idx & 7;
      int row = m0 + r; if (row >= M) row = M - 1;
      const float* src = Af32 + (size_t)row * K + kk0 + c8 * 8;
      float4 a = *(const float4*)src;
      float4 b = *(const float4*)(src + 4);
      u16x8 o;
      if (su) {
        o[0] = f2h(a.x); o[1] = f2h(a.y); o[2] = f2h(a.z); o[3] = f2h(a.w);
        o[4] = f2h(b.x); o[5] = f2h(b.y); o[6] = f2h(b.z); o[7] = f2h(b.w);
      } else {
        o[0] = f2bf(a.x); o[1] = f2bf(a.y); o[2] = f2bf(a.z); o[3] = f2bf(a.w);
        o[4] = f2bf(b.x); o[5] = f2bf(b.y); o[6] = f2bf(b.z); o[7] = f2bf(b.w);
      }
      ra[p] = o;
    }
#pragma unroll
    for (int p = 0; p < 2; ++p) {
      int idx = p * 256 + t;
      int r = idx >> 3, c8 = idx & 7;
      rb[p] = *(const u16x8*)(Bt + (size_t)r * K + kk0 + c8 * 8);
    }
  };

  auto dswrite = [&](int b) {
    char* As  = (char*)&lds[b][0];
    char* Bsc = As + 128 * 64 * 2;
#pragma unroll
    for (int p = 0; p < 4; ++p) {
      int idx = p * 256 + t;
      int r = idx >> 3, c8 = idx & 7;
      *(u16x8*)(As + r * 128 + ((c8 * 16) ^ ((r & 7) << 4))) = ra[p];
    }
#pragma unroll
    for (int p = 0; p < 2; ++p) {
      int idx = p * 256 + t;
      int r = idx >> 3, c8 = idx & 7;
      *(u16x8*)(Bsc + r * 128 + ((c8 * 16) ^ ((r & 7) << 4))) = rb[p];
    }
  };

  auto compute = [&](int b) {
    const char* As  = (const char*)&lds[b][0];
    const char* Bsc = As + 128 * 64 * 2;
#pragma unroll
    for (int ks = 0; ks < 2; ++ks) {
      int kb = ks * 64 + lk * 16;
#pragma unroll
      for (int m = 0; m < 4; ++m) {
        int rowA = wr * 64 + m * 16 + lr;
        const char* pa = As + rowA * 128 + (kb ^ ((rowA & 7) << 4));
#pragma unroll
        for (int n = 0; n < 2; ++n) {
          int rowB = wc * 32 + n * 16 + lr;
          const char* pb = Bsc + rowB * 128 + (kb ^ ((rowB & 7) << 4));
          if (su) {
            f16x8 af = *(const f16x8*)pa;
            f16x8 bf = *(const f16x8*)pb;
            acc[m][n] = __builtin_amdgcn_mfma_f32_16x16x32_f16(af, bf, acc[m][n], 0, 0, 0);
          } else {
            s16x8 af = *(const s16x8*)pa;
            s16x8 bf = *(const s16x8*)pb;
            acc[m][n] = __builtin_amdgcn_mfma_f32_16x16x32_bf16(af, bf, acc[m][n], 0, 0, 0);
          }
        }
      }
    }
  };

  loadTile(0);
  dswrite(0);
  __syncthreads();
  for (int kk = 0; kk < nK; ++kk) {
    int b = kk & 1;
    if (kk + 1 < nK) loadTile(kk + 1);
    compute(b);
    if (kk + 1 < nK) { dswrite(b ^ 1); __syncthreads(); }
  }

  u16* Cb = su ? PSo : UB;
#pragma unroll
  for (int m = 0; m < 4; ++m) {
#pragma unroll
    for (int n = 0; n < 2; ++n) {
      int col = wc * 32 + n * 16 + lr;
#pragma unroll
      for (int q = 0; q < 4; ++q) {
        int row = m0 + wr * 64 + m * 16 + lk * 4 + q;
        if (row < M)
          Cb[(size_t)row * 64 + col] = su ? f2h(acc[m][n][q]) : f2bf(acc[m][n][q]);
      }
    }
  }

  // fused column stats
  __syncthreads();
  float* sb = (float*)&lds[0][0];
#pragma unroll
  for (int n = 0; n < 2; ++n) {
    float s1 = 0.f, s2 = 0.f;
#pragma unroll
    for (int m = 0; m < 4; ++m)
#pragma unroll
      for (int q = 0; q < 4; ++q) {
        int row = m0 + wr * 64 + m * 16 + lk * 4 + q;
        float v = (row < M) ? acc[m][n][q] : 0.f;
        s1 += v; s2 += v * v;
      }
    s1 += __shfl_xor(s1, 16); s2 += __shfl_xor(s2, 16);
    s1 += __shfl_xor(s1, 32); s2 += __shfl_xor(s2, 32);
    if (lk == 0) {
      int cc = wc * 32 + n * 16 + lr;
      sb[(wr * 64 + cc) * 2 + 0] = s1;
      sb[(wr * 64 + cc) * 2 + 1] = s2;
    }
  }
  __syncthreads();
  if (t < 64) {
    float s1 = sb[t * 2]     + sb[(64 + t) * 2];
    float s2 = sb[t * 2 + 1] + sb[(64 + t) * 2 + 1];
    float* p1 = su ? p1b : p1a;
    float* p2 = su ? p2b : p2a;
    p1[(size_t)blockIdx.x * 64 + t] = s1;
    p2[(size_t)blockIdx.x * 64 + t] = s2;
  }
}

// ---------- MFMA GEMM2: BM=128 x BN=256, single-buffered LDS ----------
template<int AMODE>
__global__ __launch_bounds__(512) void k_mfma2(const u16* __restrict__ Abf, int ldA, int K, int M,
                                               const u16* __restrict__ h2, const float* __restrict__ yy,
                                               const float* __restrict__ am, const float* __restrict__ bm,
                                               const u16* __restrict__ Bt,
                                               u16* __restrict__ Cb,
                                               float* __restrict__ p1, float* __restrict__ p2) {
  __shared__ u16 lds[(128 + 256) * 64];
  int t = threadIdx.x;
  int wid = t >> 6, lane = t & 63;
  int wr = wid >> 2, wc = wid & 3;
  int lr = lane & 15, lk = lane >> 4;
  int m0 = blockIdx.x * 128;
  int nK = K >> 6;

  u16x8 ra[2];
  u16x8 rb[4];
  f32x4 acc[4][4];
#pragma unroll
  for (int m = 0; m < 4; ++m)
#pragma unroll
    for (int n = 0; n < 4; ++n) acc[m][n] = (f32x4){0.f, 0.f, 0.f, 0.f};

  auto loadTile = [&](int kk) {
    int kk0 = kk * 64;
#pragma unroll
    for (int p = 0; p < 2; ++p) {
      int idx = p * 512 + t;
      int r = idx >> 3, c8 = idx & 7;
      int row = m0 + r; if (row >= M) row = M - 1;
      int k = kk0 + c8 * 8;
      if constexpr (AMODE == 0) {
        ra[p] = *(const u16x8*)(Abf + (size_t)row * ldA + k);
      } else {
        if (kk0 < 256) {
          u16x8 h8 = *(const u16x8*)(h2 + (size_t)row * 256 + k);
          float av[8], bv[8];
          *(float4*)(av)     = *(const float4*)(am + k);
          *(float4*)(av + 4) = *(const float4*)(am + k + 4);
          *(float4*)(bv)     = *(const float4*)(bm + k);
          *(float4*)(bv + 4) = *(const float4*)(bm + k + 4);
          u16x8 o;
#pragma unroll
          for (int j = 0; j < 8; ++j) {
            float v = bf2f((u16)h8[j]) * av[j] + bv[j];
            v = v > 0.f ? v : 0.01f * v;
            o[j] = f2bf(v);
          }
          ra[p] = o;
        } else {
          float yv[8];
          *(float4*)(yv)     = *(const float4*)(yy + (size_t)row * 256 + (k - 256));
          *(float4*)(yv + 4) = *(const float4*)(yy + (size_t)row * 256 + (k - 256) + 4);
          u16x8 o;
#pragma unroll
          for (int j = 0; j < 8; ++j) o[j] = f2bf(yv[j]);
          ra[p] = o;
        }
      }
    }
#pragma unroll
    for (int p = 0; p < 4; ++p) {
      int idx = p * 512 + t;
      int r = idx >> 3, c8 = idx & 7;
      rb[p] = *(const u16x8*)(Bt + (size_t)r * K + kk0 + c8 * 8);
    }
  };

  auto dswrite = [&]() {
    char* As  = (char*)&lds[0];
    char* Bsc = As + 128 * 64 * 2;
#pragma unroll
    for (int p = 0; p < 2; ++p) {
      int idx = p * 512 + t;
      int r = idx >> 3, c8 = idx & 7;
      *(u16x8*)(As + r * 128 + ((c8 * 16) ^ ((r & 7) << 4))) = ra[p];
    }
#pragma unroll
    for (int p = 0; p < 4; ++p) {
      int idx = p * 512 + t;
      int r = idx >> 3, c8 = idx & 7;
      *(u16x8*)(Bsc + r * 128 + ((c8 * 16) ^ ((r & 7) << 4))) = rb[p];
    }
  };

  auto compute = [&]() {
    const char* As  = (const char*)&lds[0];
    const char* Bsc = As + 128 * 64 * 2;
#pragma unroll
    for (int ks = 0; ks < 2; ++ks) {
      int kb = ks * 64 + lk * 16;
      s16x8 af[4], bfr[4];
#pragma unroll
      for (int m = 0; m < 4; ++m) {
        int row = wr * 64 + m * 16 + lr;
        af[m] = *(const s16x8*)(As + row * 128 + (kb ^ ((row & 7) << 4)));
      }
#pragma unroll
      for (int n = 0; n < 4; ++n) {
        int row = wc * 64 + n * 16 + lr;
        bfr[n] = *(const s16x8*)(Bsc + row * 128 + (kb ^ ((row & 7) << 4)));
      }
#pragma unroll
      for (int m = 0; m < 4; ++m)
#pragma unroll
        for (int n = 0; n < 4; ++n)
          acc[m][n] = __builtin_amdgcn_mfma_f32_16x16x32_bf16(af[m], bfr[n], acc[m][n], 0, 0, 0);
    }
  };

  loadTile(0);
  for (int kk = 0; kk < nK; ++kk) {
    __syncthreads();
    dswrite();
    __syncthreads();
    if (kk + 1 < nK) loadTile(kk + 1);
    compute();
  }

#pragma unroll
  for (int m = 0; m < 4; ++m) {
#pragma unroll
    for (int n = 0; n < 4; ++n) {
      int col = wc * 64 + n * 16 + lr;
#pragma unroll
      for (int q = 0; q < 4; ++q) {
        int row = m0 + wr * 64 + m * 16 + lk * 4 + q;
        if (row < M) Cb[(size_t)row * 256 + col] = f2bf(acc[m][n][q]);
      }
    }
  }

  __syncthreads();
  float* sb = (float*)&lds[0];
#pragma unroll
  for (int n = 0; n < 4; ++n) {
    float s1 = 0.f, s2 = 0.f;
#pragma unroll
    for (int m = 0; m < 4; ++m)
#pragma unroll
      for (int q = 0; q < 4; ++q) {
        int row = m0 + wr * 64 + m * 16 + lk * 4 + q;
        float v = (row < M) ? acc[m][n][q] : 0.f;
        s1 += v; s2 += v * v;
      }
    s1 += __shfl_xor(s1, 16); s2 += __shfl_xor(s2, 16);
    s1 += __shfl_xor(s1, 32); s2 += __shfl_xor(s2, 32);
    if (lk == 0) {
      int c = wc * 64 + n * 16 + lr;
      sb[(wr * 256 + c) * 2 + 0] = s1;
      sb[(wr * 256 + c) * 2 + 1] = s2;
    }
  }
  __syncthreads();
  if (t < 256) {
    float s1 = sb[t * 2]     + sb[(256 + t) * 2];
    float s2 = sb[t * 2 + 1] + sb[(256 + t) * 2 + 1];
    p1[(size_t)blockIdx.x * 256 + t] = s1;
    p2[(size_t)blockIdx.x * 256 + t] = s2;
  }
}

// ---------- merged reduce: blocks 0-63 xu, 64-127 su ----------
__global__ __launch_bounds__(256) void k_reduce2(const float* __restrict__ p1a, const float* __restrict__ p2a,
                                                 const float* __restrict__ p1b, const float* __restrict__ p2b,
                                                 int nb, float invN,
                                                 const float* __restrict__ gu, const float* __restrict__ bu,
                                                 const float* __restrict__ gp, const float* __restrict__ bp,
                                                 float* __restrict__ AU, float* __restrict__ BUE,
                                                 float* __restrict__ AP, float* __restrict__ APBE) {
  int isB = blockIdx.x >> 6;
  int c = blockIdx.x & 63;
  int t = threadIdx.x;
  const float* part1 = isB ? p1b : p1a;
  const float* part2 = isB ? p2b : p2a;
  float s1 = 0.f, s2 = 0.f;
  for (int b = t; b < nb; b += 256) {
    s1 += part1[(size_t)b * 64 + c];
    s2 += part2[(size_t)b * 64 + c];
  }
  for (int m = 32; m; m >>= 1) { s1 += __shfl_xor(s1, m); s2 += __shfl_xor(s2, m); }
  __shared__ float l1[4], l2[4];
  if ((t & 63) == 0) { l1[t >> 6] = s1; l2[t >> 6] = s2; }
  __syncthreads();
  if (t == 0) {
    s1 = l1[0] + l1[1] + l1[2] + l1[3];
    s2 = l2[0] + l2[1] + l2[2] + l2[3];
    float mu  = s1 * invN;
    float var = s2 * invN - mu * mu;
    if (isB) {
      float a = gp[c] * rsqrtf(var + 1e-5f);
      AP[c] = a;
      APBE[c] = bp[c] - mu * a;
    } else {
      float a = gu[c] * rsqrtf(var + 1e-5f);
      AU[c] = a;
      BUE[c] = bu[c] - mu * a;
    }
  }
}

// ---------- reduce partials -> BN scale/shift (256 col) ----------
__global__ __launch_bounds__(256) void k_reduce_fin(const float* __restrict__ part1,
                                                    const float* __restrict__ part2,
                                                    int nb, int C, float invN,
                                                    const float* __restrict__ gamma,
                                                    const float* __restrict__ beta,
                                                    float* __restrict__ a_out,
                                                    float* __restrict__ b_out) {
  int c = blockIdx.x;
  int t = threadIdx.x;
  float s1 = 0.f, s2 = 0.f;
  for (int b = t; b < nb; b += 256) {
    s1 += part1[(size_t)b * C + c];
    s2 += part2[(size_t)b * C + c];
  }
  for (int m = 32; m; m >>= 1) { s1 += __shfl_xor(s1, m); s2 += __shfl_xor(s2, m); }
  __shared__ float l1[4], l2[4];
  if ((t & 63) == 0) { l1[t >> 6] = s1; l2[t >> 6] = s2; }
  __syncthreads();
  if (t == 0) {
    s1 = l1[0] + l1[1] + l1[2] + l1[3];
    s2 = l2[0] + l2[1] + l2[2] + l2[3];
    float mu  = s1 * invN;
    float var = s2 * invN - mu * mu;
    float a = gamma[c] * rsqrtf(var + 1e-5f);
    a_out[c] = a;
    b_out[c] = beta[c] - mu * a;
  }
}

// ---------- PS scale in place: PS = f16(ap * PS_raw) (PS rewritten each call: replay-safe) ----------
__global__ __launch_bounds__(256) void k_scaleP16(__half* __restrict__ PS, const float* __restrict__ ap, int n8) {
  for (int i = blockIdx.x * 256 + threadIdx.x; i < n8; i += gridDim.x * 256) {
    int c0 = (i & 7) * 8;
    float av[8];
    *(float4*)(av)     = *(const float4*)(ap + c0);
    *(float4*)(av + 4) = *(const float4*)(ap + c0 + 4);
    uint4 in = ((const uint4*)PS)[i];
    __half2* hp = (__half2*)&in;
    uint4 out;
    __half2* op = (__half2*)&out;
#pragma unroll
    for (int j = 0; j < 4; ++j) {
      float2 f = __half22float2(hp[j]);
      op[j] = __floats2half2_rn(f.x * av[j * 2], f.y * av[j * 2 + 1]);
    }
    ((uint4*)PS)[i] = out;
  }
}

// ---------- fused per-node: logits + softmax + RAW agg + BN + CRF solve ----------
__global__ __launch_bounds__(256) void k_nodeall(const __half* __restrict__ PS,
                                                 const int* __restrict__ srcj,
                                                 const int* __restrict__ rowptr,
                                                 const u16* __restrict__ UB,
                                                 const float* __restrict__ au,
                                                 const float* __restrict__ bue,
                                                 const float* __restrict__ minv,
                                                 int N, u16* __restrict__ HB) {
  __shared__ float mS[4096];
  __shared__ float zma[4][64];
  int t = threadIdx.x;
  for (int idx = t; idx < 1024; idx += 256)
    ((float4*)mS)[idx] = ((const float4*)minv)[idx];
  __syncthreads();

  int lane = t & 63, wid = t >> 6;
  int node = blockIdx.x * 4 + wid;
  if (node >= N) return;

  int lane8 = lane & 7, g8 = lane >> 3;
  const uint4* P4 = (const uint4*)PS;
  uint4 uv = P4[(size_t)node * 8 + lane8];
  float2 u0 = __half22float2(*(const __half2*)&uv.x);
  float2 u1 = __half22float2(((const __half2*)&uv.x)[1]);
  float2 u2 = __half22float2(*(const __half2*)&uv.z);
  float2 u3 = __half22float2(((const __half2*)&uv.z)[1]);
  float psl = __half2float(PS[(size_t)node * 64 + lane]);
  int b0 = rowptr[node], b1 = rowptr[node + 1];
  int deg = b1 - b0;
  float aggv = 0.f;
  if (deg > 0) {
    int cnt = deg < 64 ? deg : 64;
    int jj = (lane < cnt) ? srcj[b0 + lane] : 0;
    float lg = -INFINITY;
    int capbase = lane & ~7;
    int capsrc  = (lane & 7) << 3;
    for (int ss = 0; ss < cnt; ss += 8) {
      int sl = ss + g8; if (sl >= cnt) sl = cnt - 1;
      int j = __shfl(jj, sl);
      uint4 vv = P4[(size_t)j * 8 + lane8];
      float2 v0 = __half22float2(*(const __half2*)&vv.x);
      float2 v1 = __half22float2(((const __half2*)&vv.x)[1]);
      float2 v2 = __half22float2(*(const __half2*)&vv.z);
      float2 v3 = __half22float2(((const __half2*)&vv.z)[1]);
      float d0 = u0.x - v0.x, d1 = u0.y - v0.y;
      float d2 = u1.x - v1.x, d3 = u1.y - v1.y;
      float d4 = u2.x - v2.x, d5 = u2.y - v2.y;
      float d6 = u3.x - v3.x, d7 = u3.y - v3.y;
      float p = d0*d0 + d1*d1 + d2*d2 + d3*d3 + d4*d4 + d5*d5 + d6*d6 + d7*d7;
      p += __shfl_xor(p, 1, 8);
      p += __shfl_xor(p, 2, 8);
      p += __shfl_xor(p, 4, 8);
      float val = __shfl(p, capsrc);
      if (ss == capbase && lane < cnt) lg = -val;
    }
    float mx = lg;
    for (int s = b0 + 64; s < b1; ++s) {
      int j = srcj[s];
      float d = psl - __half2float(PS[(size_t)j * 64 + lane]);
      float p = d * d;
      for (int m = 32; m; m >>= 1) p += __shfl_xor(p, m);
      mx = fmaxf(mx, -p);
    }
    for (int m = 32; m; m >>= 1) mx = fmaxf(mx, __shfl_xor(mx, m));
    float ex = (lane < cnt) ? __expf(lg - mx) : 0.f;
    float sm = ex;
    for (int s = b0 + 64; s < b1; ++s) {
      int j = srcj[s];
      float d = psl - __half2float(PS[(size_t)j * 64 + lane]);
      float p = d * d;
      for (int m = 32; m; m >>= 1) p += __shfl_xor(p, m);
      if (lane == 0) sm += __expf(-p - mx);
    }
    for (int m = 32; m; m >>= 1) sm += __shfl_xor(sm, m);
    float inv = 1.0f / (sm + 1e-16f);
    float w = ex * inv;
    float acc = 0.f;
    int ss = 0;
    for (; ss + 8 <= cnt; ss += 8) {
      int   j0 = __shfl(jj, ss),     j1 = __shfl(jj, ss + 1);
      int   j2 = __shfl(jj, ss + 2), j3 = __shfl(jj, ss + 3);
      int   j4 = __shfl(jj, ss + 4), j5 = __shfl(jj, ss + 5);
      int   j6 = __shfl(jj, ss + 6), j7 = __shfl(jj, ss + 7);
      float w0 = __shfl(w, ss),      w1 = __shfl(w, ss + 1);
      float w2 = __shfl(w, ss + 2),  w3 = __shfl(w, ss + 3);
      float w4 = __shfl(w, ss + 4),  w5 = __shfl(w, ss + 5);
      float w6 = __shfl(w, ss + 6),  w7 = __shfl(w, ss + 7);
      float v0 = bf2f(UB[(size_t)j0 * 64 + lane]);
      float v1 = bf2f(UB[(size_t)j1 * 64 + lane]);
      float v2 = bf2f(UB[(size_t)j2 * 64 + lane]);
      float v3 = bf2f(UB[(size_t)j3 * 64 + lane]);
      float v4 = bf2f(UB[(size_t)j4 * 64 + lane]);
      float v5 = bf2f(UB[(size_t)j5 * 64 + lane]);
      float v6 = bf2f(UB[(size_t)j6 * 64 + lane]);
      float v7 = bf2f(UB[(size_t)j7 * 64 + lane]);
      acc += w0 * v0 + w1 * v1 + w2 * v2 + w3 * v3;
      acc += w4 * v4 + w5 * v5 + w6 * v6 + w7 * v7;
    }
    for (; ss < cnt; ++ss) {
      int j0 = __shfl(jj, ss);
      float w0 = __shfl(w, ss);
      acc += w0 * bf2f(UB[(size_t)j0 * 64 + lane]);
    }
    for (int s = b0 + 64; s < b1; ++s) {
      int j = srcj[s];
      float d = psl - __half2float(PS[(size_t)j * 64 + lane]);
      float p = d * d;
      for (int m = 32; m; m >>= 1) p += __shfl_xor(p, m);
      acc += __expf(-p - mx) * inv * bf2f(UB[(size_t)j * 64 + lane]);
    }
    aggv = au[lane] * acc + bue[lane];
  }
  float z = au[lane] * bf2f(UB[(size_t)node * 64 + lane]) + bue[lane];
  zma[wid][lane] = z - aggv;
  float h = aggv;
#pragma unroll 8
  for (int k = 0; k < 64; ++k) h += zma[wid][k] * mS[k * 64 + lane];
  HB[(size_t)node * 64 + lane] = f2bf(h);
}

// ---------- final BN + leaky: bf16 raw -> f32 out ----------
__global__ __launch_bounds__(256) void k_bnact16(const u16* __restrict__ raw, const float* __restrict__ af,
                                                 const float* __restrict__ bfp, float* __restrict__ out, int n8) {
  int i = blockIdx.x * 256 + threadIdx.x;
  int stride = gridDim.x * 256;
  for (; i < n8; i += stride) {
    int c0 = (i & 31) * 8;
    float av[8], bv[8];
    *(float4*)(av) = *(const float4*)(af + c0);  *(float4*)(av + 4) = *(const float4*)(af + c0 + 4);
    *(float4*)(bv) = *(const float4*)(bfp + c0); *(float4*)(bv + 4) = *(const float4*)(bfp + c0 + 4);
    u16x8 r = ((const u16x8*)raw)[i];
    float o[8];
#pragma unroll
    for (int j = 0; j < 8; ++j) {
      float v = bf2f((u16)r[j]) * av[j] + bv[j];
      o[j] = (v > 0.f) ? v : 0.01f * v;
    }
    ((float4*)out)[i * 2]     = *(float4*)(o);
    ((float4*)out)[i * 2 + 1] = *(float4*)(o + 4);
  }
}

extern "C" void kernel_launch(void* const* d_in, const int* in_sizes, int n_in,
                              void* d_out, int out_size, void* d_ws, size_t ws_size,
                              hipStream_t stream) {
  const float* x    = (const float*)d_in[0];
  const float* y    = (const float*)d_in[1];
  const int*   eidx = (const int*)d_in[3];
  const float* Wu   = (const float*)d_in[4];
  const float* gu   = (const float*)d_in[5];
  const float* bu   = (const float*)d_in[6];
  const float* Wp   = (const float*)d_in[7];
  const float* gp   = (const float*)d_in[8];
  const float* bp   = (const float*)d_in[9];
  const float* cIn  = (const float*)d_in[10];
  const float* Wm   = (const float*)d_in[11];
  const float* gm   = (const float*)d_in[12];
  const float* bm   = (const float*)d_in[13];
  const float* Wf   = (const float*)d_in[14];
  const float* gf   = (const float*)d_in[15];
  const float* bfv  = (const float*)d_in[16];

  const int N = in_sizes[0] / 256;
  const int E = in_sizes[3] / 2;
  const int* ei = eidx;
  const int* ej = eidx + E;

  char* ws = (char*)d_ws;
  float* MINV  = (float*)(ws + OFF_MINV);
  float* AU    = (float*)(ws + OFF_AU);
  float* BUE   = (float*)(ws + OFF_BUE);
  float* AP    = (float*)(ws + OFF_AP);
  float* APBE  = (float*)(ws + OFF_APBE);
  float* AM    = (float*)(ws + OFF_AM);
  float* BM    = (float*)(ws + OFF_BM);
  float* AF    = (float*)(ws + OFF_AF);
  float* BF    = (float*)(ws + OFF_BF);
  int*   BTOT  = (int*)(ws + OFF_BTOT);
  int*   BOFF  = (int*)(ws + OFF_BOFF);
  u16*   WUT   = (u16*)(ws + OFF_WUT);
  u16*   WMT   = (u16*)(ws + OFF_WMT);
  u16*   WFT   = (u16*)(ws + OFF_WFT);
  u16*   WPH   = (u16*)(ws + OFF_WPH);
  float* PART1A= (float*)(ws + OFF_PART1A);
  float* PART1B= (float*)(ws + OFF_PART1B);
  float* PART2A= (float*)(ws + OFF_PART2A);
  float* PART2B= (float*)(ws + OFF_PART2B);
  int*   ROWPTR= (int*)(ws + OFF_ROWPTR);
  int*   BLKCNT= (int*)(ws + OFF_BLKCNT);
  int*   BLKOFF= (int*)(ws + OFF_BLKOFF);
  u16*   HB    = (u16*)(ws + OFF_BLKCNT);    // reuse (BLKCNT/BLKOFF dead after kA3)
  int*   SRCJ  = (int*)(ws + OFF_SRCJ);
  u16*   RAWO  = (u16*)(ws + OFF_SRCJ);      // reuse (SRCJ dead after k_nodeall)
  u16*   UBRAW = (u16*)(ws + OFF_U);
  unsigned* TMP= (unsigned*)(ws + OFF_P);    // packed bins; dead after kB
  __half* PS   = (__half*)(ws + OFF_PS);     // su f16 (raw, then scaled in place)
  u16*   H2    = (u16*)(ws + OFF_H2);

  const float invN = 1.0f / (float)N;
  const int mtiles   = (N + 127) / 128;
  const int n8_64    = N * 64 / 8;
  const int n8_256   = N * 256 / 8;
  const int nbk      = (N + 255) >> 8;
  const int chunk    = (E + NBLK_BIN - 1) / NBLK_BIN;

  // weights + Minv + edge histogram in one launch
  k_tcvt_prep<<<705 + NBLK_BIN, 256, 0, stream>>>(Wu, Wm, Wf, Wp, WUT, WMT, WFT, WPH,
                                                  cIn, MINV, ei, E, chunk, BLKCNT, nbk);

  // CSR build (no global atomics)
  kA2<<<nbk, 256, 0, stream>>>(BLKCNT, nbk, BLKOFF, BTOT);
  kA2b<<<1, 512, 0, stream>>>(BTOT, BOFF, nbk);
  kA3<<<NBLK_BIN, 256, 0, stream>>>(ei, ej, E, chunk, BLKCNT, BLKOFF, BOFF, nbk, TMP);
  kB<<<nbk, 256, 0, stream>>>(TMP, BOFF, nbk, N, E, ROWPTR, SRCJ);

  // dual embedding GEMM: xu (bf16) + su (f16), one launch
  k_gemm_em<<<dim3(mtiles, 2), 256, 0, stream>>>(x, y, WUT, WPH, N, UBRAW, (u16*)PS,
                                                 PART1A, PART2A, PART1B, PART2B);

  // merged BN reduce for xu + su, then scale PS in place by ap
  k_reduce2<<<128, 256, 0, stream>>>(PART1A, PART2A, PART1B, PART2B, mtiles, invN,
                                     gu, bu, gp, bp, AU, BUE, AP, APBE);
  k_scaleP16<<<1024, 256, 0, stream>>>(PS, AP, n8_64);

  // fused logits + softmax + aggregation + BN + CRF solve -> HB
  k_nodeall<<<(N + 3) / 4, 256, 0, stream>>>(PS, SRCJ, ROWPTR, UBRAW, AU, BUE, MINV, N, HB);

  // h @ Wm -> h2 bf16
  k_mfma2<0><<<mtiles, 512, 0, stream>>>(
      HB, 64, 64, N, nullptr, nullptr, nullptr, nullptr, WMT, H2, PART1A, PART2A);
  k_reduce_fin<<<256, 256, 0, stream>>>(PART1A, PART2A, mtiles, 256, invN, gm, bm, AM, BM);

  // [leaky(bn(h2)), y] @ Wf -> raw bf16, BN + leaky -> d_out
  k_mfma2<1><<<mtiles, 512, 0, stream>>>(
      nullptr, 0, 512, N, H2, y, AM, BM, WFT, RAWO, PART1A, PART2A);
  k_reduce_fin<<<256, 256, 0, stream>>>(PART1A, PART2A, mtiles, 256, invN, gf, bfv, AF, BF);
  k_bnact16<<<2048, 256, 0, stream>>>(RAWO, AF, BF, (float*)d_out, n8_256);
}